// Round 6
// baseline (258.686 us; speedup 1.0000x reference)
//
#include <hip/hip_runtime.h>

namespace {

constexpr int B = 2, L = 4096, D = 512, H = 8, FF = 2048;
constexpr int M = B * L; // 8192
constexpr float LN_EPS = 1e-5f;

typedef __attribute__((ext_vector_type(8))) short short8;
typedef __attribute__((ext_vector_type(4))) float floatx4;

typedef __attribute__((address_space(3))) unsigned int lds_uint;
typedef const __attribute__((address_space(1))) unsigned int glob_uint;

__device__ __forceinline__ void gl_lds16(const unsigned short* g, unsigned short* l) {
  // async global->LDS, 16B/lane; LDS dest = wave-uniform base + lane*16 (m104)
  __builtin_amdgcn_global_load_lds((glob_uint*)g, (lds_uint*)l, 16, 0, 0);
}

__device__ __forceinline__ unsigned short f2bf(float f) {
  union { float f; unsigned u; } v; v.f = f;
  unsigned r = v.u + 0x7FFFu + ((v.u >> 16) & 1u);
  return (unsigned short)(r >> 16);
}

__device__ __forceinline__ float bf2f(unsigned short b) {
  union { unsigned u; float f; } v; v.u = ((unsigned)b) << 16;
  return v.f;
}

// ---------------- fused prep: x->bf16 + bias concat + weight transposes ------
__global__ __launch_bounds__(256)
void k_prep(const float* __restrict__ x,
            const float* __restrict__ Wq, const float* __restrict__ Wk,
            const float* __restrict__ Wv, const float* __restrict__ Wo,
            const float* __restrict__ W1, const float* __restrict__ W2,
            const float* __restrict__ bq, const float* __restrict__ bk,
            const float* __restrict__ bv,
            unsigned short* __restrict__ Xb,
            unsigned short* __restrict__ WqkvT, unsigned short* __restrict__ WoT,
            unsigned short* __restrict__ W1T, unsigned short* __restrict__ W2T,
            float* __restrict__ bqkv) {
  __shared__ unsigned short tile[64 * 72];
  if (blockIdx.x < 4102) {
    int tid = blockIdx.x * blockDim.x + threadIdx.x;
    if (tid < 1048576) {  // x: 4 elems per thread (M*D = 4194304)
      float4 v = ((const float4*)x)[tid];
      ((ushort4*)Xb)[tid] = make_ushort4(f2bf(v.x), f2bf(v.y), f2bf(v.z), f2bf(v.w));
      return;
    }
    int u = tid - 1048576;
    if (u < 1536) bqkv[u] = (u < 512) ? bq[u] : (u < 1024 ? bk[u - 512] : bv[u - 1024]);
    return;
  }
  const int t = blockIdx.x - 4102;
  const float* src; unsigned short* dst; int Ns, Kd, n0, k0, nsrc0;
  if (t < 192) {        // WqkvT [1536][512] from Wq/Wk/Wv [512][512]
    int nt = t % 24, kt = t / 24; int ng = nt * 64;
    src = ng < 512 ? Wq : (ng < 1024 ? Wk : Wv);
    Ns = 512; Kd = 512; n0 = ng; nsrc0 = ng & 511; k0 = kt * 64; dst = WqkvT;
  } else if (t < 256) { // WoT [512][512] from Wo [512][512]
    int u = t - 192; int nt = u % 8, kt = u / 8;
    src = Wo; Ns = 512; Kd = 512; n0 = nt * 64; nsrc0 = n0; k0 = kt * 64; dst = WoT;
  } else if (t < 512) { // W1T [2048][512] from W1 [512][2048]
    int u = t - 256; int nt = u % 32, kt = u / 32;
    src = W1; Ns = 2048; Kd = 512; n0 = nt * 64; nsrc0 = n0; k0 = kt * 64; dst = W1T;
  } else {              // W2T [512][2048] from W2 [2048][512]
    int u = t - 512; int nt = u % 8, kt = u / 8;
    src = W2; Ns = 512; Kd = 2048; n0 = nt * 64; nsrc0 = n0; k0 = kt * 64; dst = W2T;
  }
  const int tid = threadIdx.x;
  {
    int r = tid >> 2, cs = (tid & 3) * 16;  // src row k0+r, 16 cols
    const float4* sp = (const float4*)(src + (size_t)(k0 + r) * Ns + nsrc0 + cs);
    unsigned short* tp = &tile[r * 72 + cs];
#pragma unroll
    for (int i = 0; i < 4; ++i) {
      float4 v = sp[i];
      tp[i * 4 + 0] = f2bf(v.x); tp[i * 4 + 1] = f2bf(v.y);
      tp[i * 4 + 2] = f2bf(v.z); tp[i * 4 + 3] = f2bf(v.w);
    }
  }
  __syncthreads();
  {
    int n = tid >> 2, ks = (tid & 3) * 16;  // dst row n0+n, 16 k's
    unsigned short buf[16];
#pragma unroll
    for (int e = 0; e < 16; ++e) buf[e] = tile[(ks + e) * 72 + n];
    unsigned short* dp = dst + (size_t)(n0 + n) * Kd + k0 + ks;
    *(short8*)dp = *(const short8*)&buf[0];
    *(short8*)(dp + 8) = *(const short8*)&buf[8];
  }
}

// ---------------- bf16 MFMA GEMM (double-buffered DMA staging) ---------------
// EPI: 0 = bf16 out, 1 = bf16 out + ReLU, 2 = f32 out (split-K or single-z),
//      3 = QKV fused: Q cols scaled by 1/sqrt(HD) (attn scale folded in),
//          Q/K cols -> Cout (bf16), V cols -> Vout TRANSPOSED ([b][h][d][key]).
// Block ids are XCD-chunk remapped (T1).
template <int EPI>
__global__ __launch_bounds__(256, 3)
void k_gemm(const unsigned short* __restrict__ A, const unsigned short* __restrict__ BT,
            const float* __restrict__ bias, void* __restrict__ Cout,
            unsigned short* __restrict__ Vout,
            const int klen, const int N) {
  __shared__ unsigned short lA[2][128 * 32];
  __shared__ unsigned short lB[2][128 * 32];
  // XCD-chunked bijective remap (all grids have total % 8 == 0)
  unsigned flat = blockIdx.x + gridDim.x * (blockIdx.y + gridDim.y * blockIdx.z);
  const unsigned chunk = (gridDim.x * gridDim.y * gridDim.z) >> 3;
  flat = (flat & 7) * chunk + (flat >> 3);
  const unsigned bx = flat % gridDim.x;
  const unsigned rest = flat / gridDim.x;
  const unsigned by = rest % gridDim.y;
  const unsigned bz = rest / gridDim.y;

  const int tid = threadIdx.x;
  const int wave = tid >> 6, lane = tid & 63;
  const int quad = lane >> 4, l16 = lane & 15;
  const int m0 = by * 128, n0 = bx * 128;
  const int wm = (wave >> 1) * 64, wn = (wave & 1) * 64;
  const int kbeg = bz * klen;
  const size_t Kdim = (size_t)klen * gridDim.z;

  const floatx4 fzero = {0.f, 0.f, 0.f, 0.f};
  floatx4 acc[4][4];
#pragma unroll
  for (int i = 0; i < 4; ++i)
#pragma unroll
    for (int j = 0; j < 4; ++j) acc[i][j] = fzero;

  const int r0 = tid >> 2, o0 = (tid & 3) * 8;
  const int r1 = (256 + tid) >> 2, o1 = (tid & 3) * 8;
  const unsigned short* Ag0 = A + (size_t)(m0 + r0) * Kdim + kbeg + o0;
  const unsigned short* Ag1 = A + (size_t)(m0 + r1) * Kdim + kbeg + o1;
  const unsigned short* Bg0 = BT + (size_t)(n0 + r0) * Kdim + kbeg + o0;
  const unsigned short* Bg1 = BT + (size_t)(n0 + r1) * Kdim + kbeg + o1;

  auto stage = [&](int buf, int kt) {
    gl_lds16(Ag0 + kt, &lA[buf][wave * 512]);
    gl_lds16(Ag1 + kt, &lA[buf][(4 + wave) * 512]);
    gl_lds16(Bg0 + kt, &lB[buf][wave * 512]);
    gl_lds16(Bg1 + kt, &lB[buf][(4 + wave) * 512]);
  };

  stage(0, 0);
  __syncthreads();  // drain first tile's DMA

  int buf = 0;
  for (int kt = 0; kt < klen; kt += 32, buf ^= 1) {
    if (kt + 32 < klen) stage(buf ^ 1, kt + 32);  // async prefetch of next tile
    short8 af[4], bf[4];
#pragma unroll
    for (int i = 0; i < 4; ++i)
      af[i] = *(const short8*)&lA[buf][(wm + i * 16 + l16) * 32 + quad * 8];
#pragma unroll
    for (int j = 0; j < 4; ++j)
      bf[j] = *(const short8*)&lB[buf][(wn + j * 16 + l16) * 32 + quad * 8];
#pragma unroll
    for (int i = 0; i < 4; ++i)
#pragma unroll
      for (int j = 0; j < 4; ++j)
        acc[i][j] = __builtin_amdgcn_mfma_f32_16x16x32_bf16(af[i], bf[j], acc[i][j], 0, 0, 0);
    __syncthreads();  // drains prefetch DMA + guards buffer reuse
  }

  float* outf = (float*)Cout + (size_t)bz * M * N;
  const bool vblock = (EPI == 3) && (n0 >= 1024);  // block-uniform
  const float qscale = (EPI == 3 && n0 < 512) ? 0.125f : 1.f;  // Q cols pre-scaled
#pragma unroll
  for (int j = 0; j < 4; ++j) {
    const int col = n0 + wn + j * 16 + l16;
    const float bv = (bz == 0) ? bias[col] : 0.f;
#pragma unroll
    for (int i = 0; i < 4; ++i) {
      const int row = m0 + wm + i * 16 + quad * 4;
      if (EPI == 3 && vblock) {
        const int hh = (col - 1024) >> 6, dd = (col - 1024) & 63;
        const int bb = row >> 12, keyl = row & 4095;  // 128-tiles never cross b
        ushort4 pk = make_ushort4(f2bf(acc[i][j][0] + bv), f2bf(acc[i][j][1] + bv),
                                  f2bf(acc[i][j][2] + bv), f2bf(acc[i][j][3] + bv));
        *(ushort4*)(Vout + ((size_t)(bb * 8 + hh) * 64 + dd) * L + keyl) = pk;
      } else {
#pragma unroll
        for (int r = 0; r < 4; ++r) {
          float v = acc[i][j][r] + bv;
          if (EPI == 1) v = fmaxf(v, 0.f);
          if (EPI == 3) v *= qscale;
          if (EPI == 2)
            outf[(size_t)(row + r) * N + col] = v;
          else
            ((unsigned short*)Cout)[(size_t)(row + r) * N + col] = f2bf(v);
        }
      }
    }
  }
}

// ---------------- banded flash attention (v10b) -------------------------------
// v9 structure (swapped QK^T, zero-LDS P, XCD chunking, cvt_pk) plus:
// Q pre-scaled in QKV epilogue, and per-wave DEAD-HALF SKIP (union-based
// alive0/alive1). FIX vs v10: `fast` must bound the MAX pair distance
// (q0+15-jbg and jbg+63-q0), not the union-range endpoints -- the union test
// admitted pairs at distance W+1..W+15 (round-4 absmax 0.258 failure).
__global__ __launch_bounds__(256, 4)
void k_attn(const unsigned short* __restrict__ QKV, const unsigned short* __restrict__ Vg,
            unsigned short* __restrict__ attnb, const int* __restrict__ wptr) {
  const int W = wptr[0];  // 128
  __shared__ unsigned short Kt[2][4096];  // [key][slot], slot = dpart ^ sw2(key)
  __shared__ unsigned short Vt[2][4096];  // [d][slot],   slot = kpart ^ (d&7)
  const int tid = threadIdx.x;
  const int wave = tid >> 6, lane = tid & 63;
  const int quad = lane >> 4, l16 = lane & 15;
  const int bid = (int)((blockIdx.x & 7) * (gridDim.x >> 3) + (blockIdx.x >> 3));
  const int qt = bid & 63, h = (bid >> 6) & 7, b = bid >> 9;  // qt fastest
  const int q0blk = qt * 64;
  const int q0 = q0blk + wave * 16;

  const unsigned short* Kbase = QKV + (size_t)(b * L) * 1536 + 512 + h * 64;
  const unsigned short* Vh = Vg + (size_t)(b * 8 + h) * 64 * L;  // [d][key]

  auto stage = [&](int buf, int jbg) {
#pragma unroll
    for (int i = 0; i < 2; ++i) {
      int c = i * 256 + tid;
      int kr = c >> 3;
      int key = jbg + kr;
      int keyc = key < 0 ? 0 : (key > L - 1 ? L - 1 : key);  // P=0 there
      int dpart = (c & 7) ^ (kr & 7) ^ (((kr >> 3) & 3) << 1);  // inv of sw2
      gl_lds16(Kbase + (size_t)keyc * 1536 + dpart * 8,
               &Kt[buf][(i * 256 + wave * 64) * 8]);
    }
#pragma unroll
    for (int i = 0; i < 2; ++i) {
      int c = i * 256 + tid;
      int d = c >> 3;
      int kpart = (c & 7) ^ (d & 7);
      int kb = jbg + kpart * 8;
      kb = kb < 0 ? 0 : (kb > L - 8 ? L - 8 : kb);  // 8-aligned, P=0 where invalid
      gl_lds16(Vh + (size_t)d * L + kb,
               &Vt[buf][(i * 256 + wave * 64) * 8]);
    }
  };

  const unsigned short* Qp = QKV + (size_t)(b * L + q0 + l16) * 1536 + h * 64;
  short8 qf0 = *(const short8*)(Qp + quad * 8);
  short8 qf1 = *(const short8*)(Qp + 32 + quad * 8);

  int koff[4][2];
#pragma unroll
  for (int tt = 0; tt < 4; ++tt) {
    int krow = (tt >> 1) * 32 + ((l16 >> 2) << 3) + (tt & 1) * 4 + (l16 & 3);
    int s2 = (krow & 7) ^ (((krow >> 3) & 3) << 1);
    koff[tt][0] = (krow * 8 + (quad ^ s2)) * 8;
    koff[tt][1] = (krow * 8 + ((quad + 4) ^ s2)) * 8;
  }
  int voff[4][2];
#pragma unroll
  for (int nt = 0; nt < 4; ++nt) {
    int d = nt * 16 + l16;
    voff[nt][0] = (d * 8 + (quad ^ (d & 7))) * 8;
    voff[nt][1] = (d * 8 + ((quad + 4) ^ (d & 7))) * 8;
  }

  const floatx4 fzero = {0.f, 0.f, 0.f, 0.f};
  floatx4 o[4];
#pragma unroll
  for (int i = 0; i < 4; ++i) o[i] = fzero;
  float lsum = 0.f;
  const int q = q0 + l16;

  stage(0, q0blk - 128);
  __syncthreads();

  for (int it = 0; it < 5; ++it) {  // 5 x 64-key tiles cover the 320-key band
    const int jbg = q0blk - 128 + it * 64;
    if (it < 4) stage((it + 1) & 1, jbg + 64);  // prefetch next tile (async DMA)
    const unsigned short* lk = Kt[it & 1];
    const unsigned short* lv = Vt[it & 1];
    // wave-uniform union-valid key range (tile-relative) -> dead-half skip
    int lo = q0 - W - jbg;       if (-jbg > lo) lo = -jbg;
    int hi = q0 + 15 + W - jbg;  if (L - 1 - jbg < hi) hi = L - 1 - jbg;
    const bool alive0 = (hi >= 0) && (lo <= 31);   // keys 0..31 of tile
    const bool alive1 = (hi >= 32) && (lo <= 63);  // keys 32..63
    // fast (no per-element mask) requires the MAX pair distance within band:
    const bool fast = (jbg >= 0) && (jbg + 64 <= L) &&
                      (q0 + 15 - jbg <= W) && (jbg + 63 - q0 <= W);
    unsigned pu[8];
    union { unsigned u[4]; short8 v; } pa0, pa1;
#pragma unroll
    for (int tt = 0; tt < 4; ++tt) {
      if (tt < 2 ? !alive0 : !alive1) continue;  // wave-uniform skip
      const short8 kf0 = *(const short8*)&lk[koff[tt][0]];
      const short8 kf1 = *(const short8*)&lk[koff[tt][1]];
      floatx4 z = fzero;
      z = __builtin_amdgcn_mfma_f32_16x16x32_bf16(kf0, qf0, z, 0, 0, 0);
      z = __builtin_amdgcn_mfma_f32_16x16x32_bf16(kf1, qf1, z, 0, 0, 0);
      float pv[4];
      if (fast) {
#pragma unroll
        for (int r = 0; r < 4; ++r) {
          float p = __expf(z[r]);  // Q pre-scaled by 1/sqrt(HD)
          lsum += p;
          pv[r] = p;
        }
      } else {
        const int kb0 = jbg + (tt >> 1) * 32 + quad * 8 + (tt & 1) * 4;
#pragma unroll
        for (int r = 0; r < 4; ++r) {
          int key = kb0 + r;
          int dd = q - key; dd = dd < 0 ? -dd : dd;
          bool okk = (key >= 0) && (key < L) && (dd <= W);
          float p = okk ? __expf(z[r]) : 0.f;  // fixed m=0, masked to 0
          lsum += p;
          pv[r] = p;
        }
      }
      unsigned lo2, hi2;  // v_cvt_pk_bf16_f32: src0 -> low 16, src1 -> high 16 (RNE)
      asm("v_cvt_pk_bf16_f32 %0, %1, %2" : "=v"(lo2) : "v"(pv[0]), "v"(pv[1]));
      asm("v_cvt_pk_bf16_f32 %0, %1, %2" : "=v"(hi2) : "v"(pv[2]), "v"(pv[3]));
      pu[tt * 2 + 0] = lo2;
      pu[tt * 2 + 1] = hi2;
    }
    if (alive0) { pa0.u[0] = pu[0]; pa0.u[1] = pu[1]; pa0.u[2] = pu[2]; pa0.u[3] = pu[3]; }
    if (alive1) { pa1.u[0] = pu[4]; pa1.u[1] = pu[5]; pa1.u[2] = pu[6]; pa1.u[3] = pu[7]; }
    if (alive0 || alive1) {
#pragma unroll
      for (int nt = 0; nt < 4; ++nt) {
        if (alive0) {
          const short8 vf0 = *(const short8*)&lv[voff[nt][0]];
          o[nt] = __builtin_amdgcn_mfma_f32_16x16x32_bf16(pa0.v, vf0, o[nt], 0, 0, 0);
        }
        if (alive1) {
          const short8 vf1 = *(const short8*)&lv[voff[nt][1]];
          o[nt] = __builtin_amdgcn_mfma_f32_16x16x32_bf16(pa1.v, vf1, o[nt], 0, 0, 0);
        }
      }
    }
    __syncthreads();  // drains next-tile DMA + guards buffer reuse
  }
  // row-sum: lane holds disjoint key subsets for q=q0+l16 -> reduce over quads
  lsum += __shfl_xor(lsum, 16, 64);
  lsum += __shfl_xor(lsum, 32, 64);
#pragma unroll
  for (int r = 0; r < 4; ++r) {
    float inv = 1.f / __shfl(lsum, quad * 4 + r, 64);  // sum for q=q0+quad*4+r
    size_t base = (size_t)(b * L + q0 + quad * 4 + r) * 512 + h * 64;
#pragma unroll
    for (int nt = 0; nt < 4; ++nt)
      attnb[base + nt * 16 + l16] = f2bf(o[nt][r] * inv);
  }
}

// ---------------- fused residual + LayerNorm ----------------------------------
// y = t0 (+ t1 if non-null) + res; out = LN(y)*g+b. RESBF: res is bf16.
template <int RESBF>
__global__ __launch_bounds__(256, 2)
void k_res_ln(const float* __restrict__ t0, const float* __restrict__ t1,
              const void* __restrict__ res,
              const float* __restrict__ gamma, const float* __restrict__ beta,
              float* __restrict__ outf, unsigned short* __restrict__ outb) {
  const int wave = threadIdx.x >> 6, lane = threadIdx.x & 63;
  const int row = blockIdx.x * 4 + wave;
  const float4* tv = (const float4*)(t0 + (size_t)row * D);
  float4 a0 = tv[lane], a1 = tv[lane + 64];
  float4 b0, b1;
  if (RESBF) {
    const ushort4* rv = (const ushort4*)((const unsigned short*)res + (size_t)row * D);
    ushort4 u0 = rv[lane], u1 = rv[lane + 64];
    b0 = make_float4(bf2f(u0.x), bf2f(u0.y), bf2f(u0.z), bf2f(u0.w));
    b1 = make_float4(bf2f(u1.x), bf2f(u1.y), bf2f(u1.z), bf2f(u1.w));
  } else {
    const float4* rv = (const float4*)((const float*)res + (size_t)row * D);
    b0 = rv[lane]; b1 = rv[lane + 64];
  }
  float4 y0 = make_float4(a0.x + b0.x, a0.y + b0.y, a0.z + b0.z, a0.w + b0.w);
  float4 y1 = make_float4(a1.x + b1.x, a1.y + b1.y, a1.z + b1.z, a1.w + b1.w);
  if (t1) {
    const float4* uv = (const float4*)(t1 + (size_t)row * D);
    float4 c0 = uv[lane], c1 = uv[lane + 64];
    y0.x += c0.x; y0.y += c0.y; y0.z += c0.z; y0.w += c0.w;
    y1.x += c1.x; y1.y += c1.y; y1.z += c1.z; y1.w += c1.w;
  }
  float s = y0.x + y0.y + y0.z + y0.w + y1.x + y1.y + y1.z + y1.w;
  float q = y0.x * y0.x + y0.y * y0.y + y0.z * y0.z + y0.w * y0.w +
            y1.x * y1.x + y1.y * y1.y + y1.z * y1.z + y1.w * y1.w;
#pragma unroll
  for (int d = 1; d < 64; d <<= 1) {
    s += __shfl_xor(s, d, 64);
    q += __shfl_xor(q, d, 64);
  }
  const float mean = s * (1.f / D);
  const float var = q * (1.f / D) - mean * mean;
  const float rstd = rsqrtf(var + LN_EPS);
  float4 g0 = ((const float4*)gamma)[lane], g1 = ((const float4*)gamma)[lane + 64];
  float4 e0 = ((const float4*)beta)[lane], e1 = ((const float4*)beta)[lane + 64];
  float4 o0 = make_float4((y0.x - mean) * rstd * g0.x + e0.x, (y0.y - mean) * rstd * g0.y + e0.y,
                          (y0.z - mean) * rstd * g0.z + e0.z, (y0.w - mean) * rstd * g0.w + e0.w);
  float4 o1 = make_float4((y1.x - mean) * rstd * g1.x + e1.x, (y1.y - mean) * rstd * g1.y + e1.y,
                          (y1.z - mean) * rstd * g1.z + e1.z, (y1.w - mean) * rstd * g1.w + e1.w);
  if (outf) {
    ((float4*)(outf + (size_t)row * D))[lane] = o0;
    ((float4*)(outf + (size_t)row * D))[lane + 64] = o1;
  }
  if (outb) {
    ((ushort4*)(outb + (size_t)row * D))[lane] =
        make_ushort4(f2bf(o0.x), f2bf(o0.y), f2bf(o0.z), f2bf(o0.w));
    ((ushort4*)(outb + (size_t)row * D))[lane + 64] =
        make_ushort4(f2bf(o1.x), f2bf(o1.y), f2bf(o1.z), f2bf(o1.w));
  }
}

}  // namespace

extern "C" void kernel_launch(void* const* d_in, const int* in_sizes, int n_in,
                              void* d_out, int out_size, void* d_ws, size_t ws_size,
                              hipStream_t stream) {
  const float* x   = (const float*)d_in[0];
  const float* Wq  = (const float*)d_in[1];
  const float* bq  = (const float*)d_in[2];
  const float* Wk  = (const float*)d_in[3];
  const float* bk  = (const float*)d_in[4];
  const float* Wv  = (const float*)d_in[5];
  const float* bv  = (const float*)d_in[6];
  const float* Wo  = (const float*)d_in[7];
  const float* bo  = (const float*)d_in[8];
  const float* g1  = (const float*)d_in[9];
  const float* be1 = (const float*)d_in[10];
  const float* W1  = (const float*)d_in[11];
  const float* b1  = (const float*)d_in[12];
  const float* W2  = (const float*)d_in[13];
  const float* b2  = (const float*)d_in[14];
  const float* g2  = (const float*)d_in[15];
  const float* be2 = (const float*)d_in[16];
  const int* wptr  = (const int*)d_in[17];
  float* out = (float*)d_out;

  char* w = (char*)d_ws;
  size_t off = 0;
  auto take = [&](size_t bytes) -> void* {
    void* p = w + off;
    off += (bytes + 255) & ~(size_t)255;
    return p;
  };
  unsigned short* Xb    = (unsigned short*)take((size_t)M * D * 2);      // 8 MiB
  unsigned short* QKVb  = (unsigned short*)take((size_t)M * 1536 * 2);   // 24 MiB
  unsigned short* attnb = (unsigned short*)take((size_t)M * D * 2);      // 8 MiB
  unsigned short* Vg    = (unsigned short*)take((size_t)M * D * 2);      // 8 MiB (V^T per head)
  unsigned short* WqkvT = (unsigned short*)take((size_t)1536 * 512 * 2); // 1.5 MiB
  unsigned short* WoT   = (unsigned short*)take((size_t)512 * 512 * 2);  // 0.5 MiB
  unsigned short* W1T   = (unsigned short*)take((size_t)2048 * 512 * 2); // 2 MiB
  unsigned short* W2T   = (unsigned short*)take((size_t)512 * 2048 * 2); // 2 MiB
  float* bqkv           = (float*)take(1536 * 4);
  float* tbuf           = (float*)take((size_t)2 * M * D * 4);           // 32 MiB (2 split-K partials)
  unsigned short* hb    = (unsigned short*)take((size_t)M * D * 2);      // 8 MiB
  unsigned short* ffb   = (unsigned short*)take((size_t)M * FF * 2);     // 32 MiB

  k_prep<<<4870, 256, 0, stream>>>(x, Wq, Wk, Wv, Wo, W1, W2, bq, bk, bv,
                                   Xb, WqkvT, WoT, W1T, W2T, bqkv);
  // QKV: Q (pre-scaled) / K -> QKVb, V -> Vg transposed
  k_gemm<3><<<dim3(12, 64, 1), 256, 0, stream>>>(Xb, WqkvT, bqkv, QKVb, Vg, 512, 1536);
  k_attn<<<B * H * (L / 64), 256, 0, stream>>>(QKVb, Vg, attnb, wptr);
  // Wo: single-z f32 out (no split-K partials; halves the tbuf round-trip)
  k_gemm<2><<<dim3(4, 64, 1), 256, 0, stream>>>(attnb, WoT, bo, tbuf, nullptr, 512, 512);
  // h = LN1(x + t0) -> hb (bf16 only; fp32 h dropped)
  k_res_ln<0><<<M / 4, 256, 0, stream>>>(tbuf, nullptr, x, g1, be1, nullptr, hb);
  k_gemm<1><<<dim3(16, 64, 1), 256, 0, stream>>>(hb, W1T, b1, ffb, nullptr, 512, 2048);
  k_gemm<2><<<dim3(4, 64, 2), 256, 0, stream>>>(ffb, W2T, b2, tbuf, nullptr, 1024, 512);
  // out = LN2(hb + t0 + t1), residual from bf16 h
  k_res_ln<1><<<M / 4, 256, 0, stream>>>(tbuf, tbuf + (size_t)M * D, hb, g2, be2, out, nullptr);
}

// Round 7
// 234.485 us; speedup vs baseline: 1.1032x; 1.1032x over previous
//
#include <hip/hip_runtime.h>

namespace {

constexpr int B = 2, L = 4096, D = 512, H = 8, FF = 2048;
constexpr int M = B * L; // 8192
constexpr float LN_EPS = 1e-5f;

typedef __attribute__((ext_vector_type(8))) short short8;
typedef __attribute__((ext_vector_type(4))) float floatx4;

typedef __attribute__((address_space(3))) unsigned int lds_uint;
typedef const __attribute__((address_space(1))) unsigned int glob_uint;

__device__ __forceinline__ void gl_lds16(const unsigned short* g, unsigned short* l) {
  // async global->LDS, 16B/lane; LDS dest = wave-uniform base + lane*16 (m104)
  __builtin_amdgcn_global_load_lds((glob_uint*)g, (lds_uint*)l, 16, 0, 0);
}

__device__ __forceinline__ unsigned short f2bf(float f) {
  union { float f; unsigned u; } v; v.f = f;
  unsigned r = v.u + 0x7FFFu + ((v.u >> 16) & 1u);
  return (unsigned short)(r >> 16);
}

__device__ __forceinline__ float bf2f(unsigned short b) {
  union { unsigned u; float f; } v; v.u = ((unsigned)b) << 16;
  return v.f;
}

// ---------------- fused prep: x->bf16 + bias concat + weight transposes ------
__global__ __launch_bounds__(256)
void k_prep(const float* __restrict__ x,
            const float* __restrict__ Wq, const float* __restrict__ Wk,
            const float* __restrict__ Wv, const float* __restrict__ Wo,
            const float* __restrict__ W1, const float* __restrict__ W2,
            const float* __restrict__ bq, const float* __restrict__ bk,
            const float* __restrict__ bv,
            unsigned short* __restrict__ Xb,
            unsigned short* __restrict__ WqkvT, unsigned short* __restrict__ WoT,
            unsigned short* __restrict__ W1T, unsigned short* __restrict__ W2T,
            float* __restrict__ bqkv) {
  __shared__ unsigned short tile[64 * 72];
  if (blockIdx.x < 4102) {
    int tid = blockIdx.x * blockDim.x + threadIdx.x;
    if (tid < 1048576) {  // x: 4 elems per thread (M*D = 4194304)
      float4 v = ((const float4*)x)[tid];
      ((ushort4*)Xb)[tid] = make_ushort4(f2bf(v.x), f2bf(v.y), f2bf(v.z), f2bf(v.w));
      return;
    }
    int u = tid - 1048576;
    if (u < 1536) bqkv[u] = (u < 512) ? bq[u] : (u < 1024 ? bk[u - 512] : bv[u - 1024]);
    return;
  }
  const int t = blockIdx.x - 4102;
  const float* src; unsigned short* dst; int Ns, Kd, n0, k0, nsrc0;
  if (t < 192) {        // WqkvT [1536][512] from Wq/Wk/Wv [512][512]
    int nt = t % 24, kt = t / 24; int ng = nt * 64;
    src = ng < 512 ? Wq : (ng < 1024 ? Wk : Wv);
    Ns = 512; Kd = 512; n0 = ng; nsrc0 = ng & 511; k0 = kt * 64; dst = WqkvT;
  } else if (t < 256) { // WoT [512][512] from Wo [512][512]
    int u = t - 192; int nt = u % 8, kt = u / 8;
    src = Wo; Ns = 512; Kd = 512; n0 = nt * 64; nsrc0 = n0; k0 = kt * 64; dst = WoT;
  } else if (t < 512) { // W1T [2048][512] from W1 [512][2048]
    int u = t - 256; int nt = u % 32, kt = u / 32;
    src = W1; Ns = 2048; Kd = 512; n0 = nt * 64; nsrc0 = n0; k0 = kt * 64; dst = W1T;
  } else {              // W2T [512][2048] from W2 [2048][512]
    int u = t - 512; int nt = u % 8, kt = u / 8;
    src = W2; Ns = 512; Kd = 2048; n0 = nt * 64; nsrc0 = n0; k0 = kt * 64; dst = W2T;
  }
  const int tid = threadIdx.x;
  {
    int r = tid >> 2, cs = (tid & 3) * 16;  // src row k0+r, 16 cols
    const float4* sp = (const float4*)(src + (size_t)(k0 + r) * Ns + nsrc0 + cs);
    unsigned short* tp = &tile[r * 72 + cs];
#pragma unroll
    for (int i = 0; i < 4; ++i) {
      float4 v = sp[i];
      tp[i * 4 + 0] = f2bf(v.x); tp[i * 4 + 1] = f2bf(v.y);
      tp[i * 4 + 2] = f2bf(v.z); tp[i * 4 + 3] = f2bf(v.w);
    }
  }
  __syncthreads();
  {
    int n = tid >> 2, ks = (tid & 3) * 16;  // dst row n0+n, 16 k's
    unsigned short buf[16];
#pragma unroll
    for (int e = 0; e < 16; ++e) buf[e] = tile[(ks + e) * 72 + n];
    unsigned short* dp = dst + (size_t)(n0 + n) * Kd + k0 + ks;
    *(short8*)dp = *(const short8*)&buf[0];
    *(short8*)(dp + 8) = *(const short8*)&buf[8];
  }
}

// ---------------- bf16 MFMA GEMM (double-buffered DMA staging) ---------------
// EPI: 0 = bf16 out, 1 = bf16 out + ReLU, 2 = f32 out (split-K partials),
//      3 = QKV fused: Q cols scaled by 1/sqrt(HD) (attn scale folded in),
//          Q/K cols -> Cout (bf16), V cols -> Vout TRANSPOSED ([b][h][d][key]).
// Block ids are XCD-chunk remapped (T1).
template <int EPI>
__global__ __launch_bounds__(256, 3)
void k_gemm(const unsigned short* __restrict__ A, const unsigned short* __restrict__ BT,
            const float* __restrict__ bias, void* __restrict__ Cout,
            unsigned short* __restrict__ Vout,
            const int klen, const int N) {
  __shared__ unsigned short lA[2][128 * 32];
  __shared__ unsigned short lB[2][128 * 32];
  // XCD-chunked bijective remap (all grids have total % 8 == 0)
  unsigned flat = blockIdx.x + gridDim.x * (blockIdx.y + gridDim.y * blockIdx.z);
  const unsigned chunk = (gridDim.x * gridDim.y * gridDim.z) >> 3;
  flat = (flat & 7) * chunk + (flat >> 3);
  const unsigned bx = flat % gridDim.x;
  const unsigned rest = flat / gridDim.x;
  const unsigned by = rest % gridDim.y;
  const unsigned bz = rest / gridDim.y;

  const int tid = threadIdx.x;
  const int wave = tid >> 6, lane = tid & 63;
  const int quad = lane >> 4, l16 = lane & 15;
  const int m0 = by * 128, n0 = bx * 128;
  const int wm = (wave >> 1) * 64, wn = (wave & 1) * 64;
  const int kbeg = bz * klen;
  const size_t Kdim = (size_t)klen * gridDim.z;

  const floatx4 fzero = {0.f, 0.f, 0.f, 0.f};
  floatx4 acc[4][4];
#pragma unroll
  for (int i = 0; i < 4; ++i)
#pragma unroll
    for (int j = 0; j < 4; ++j) acc[i][j] = fzero;

  const int r0 = tid >> 2, o0 = (tid & 3) * 8;
  const int r1 = (256 + tid) >> 2, o1 = (tid & 3) * 8;
  const unsigned short* Ag0 = A + (size_t)(m0 + r0) * Kdim + kbeg + o0;
  const unsigned short* Ag1 = A + (size_t)(m0 + r1) * Kdim + kbeg + o1;
  const unsigned short* Bg0 = BT + (size_t)(n0 + r0) * Kdim + kbeg + o0;
  const unsigned short* Bg1 = BT + (size_t)(n0 + r1) * Kdim + kbeg + o1;

  auto stage = [&](int buf, int kt) {
    gl_lds16(Ag0 + kt, &lA[buf][wave * 512]);
    gl_lds16(Ag1 + kt, &lA[buf][(4 + wave) * 512]);
    gl_lds16(Bg0 + kt, &lB[buf][wave * 512]);
    gl_lds16(Bg1 + kt, &lB[buf][(4 + wave) * 512]);
  };

  stage(0, 0);
  __syncthreads();  // drain first tile's DMA

  int buf = 0;
  for (int kt = 0; kt < klen; kt += 32, buf ^= 1) {
    if (kt + 32 < klen) stage(buf ^ 1, kt + 32);  // async prefetch of next tile
    short8 af[4], bf[4];
#pragma unroll
    for (int i = 0; i < 4; ++i)
      af[i] = *(const short8*)&lA[buf][(wm + i * 16 + l16) * 32 + quad * 8];
#pragma unroll
    for (int j = 0; j < 4; ++j)
      bf[j] = *(const short8*)&lB[buf][(wn + j * 16 + l16) * 32 + quad * 8];
#pragma unroll
    for (int i = 0; i < 4; ++i)
#pragma unroll
      for (int j = 0; j < 4; ++j)
        acc[i][j] = __builtin_amdgcn_mfma_f32_16x16x32_bf16(af[i], bf[j], acc[i][j], 0, 0, 0);
    __syncthreads();  // drains prefetch DMA + guards buffer reuse
  }

  float* outf = (float*)Cout + (size_t)bz * M * N;
  const bool vblock = (EPI == 3) && (n0 >= 1024);  // block-uniform
  const float qscale = (EPI == 3 && n0 < 512) ? 0.125f : 1.f;  // Q cols pre-scaled
#pragma unroll
  for (int j = 0; j < 4; ++j) {
    const int col = n0 + wn + j * 16 + l16;
    const float bv = (bz == 0) ? bias[col] : 0.f;
#pragma unroll
    for (int i = 0; i < 4; ++i) {
      const int row = m0 + wm + i * 16 + quad * 4;
      if (EPI == 3 && vblock) {
        const int hh = (col - 1024) >> 6, dd = (col - 1024) & 63;
        const int bb = row >> 12, keyl = row & 4095;  // 128-tiles never cross b
        ushort4 pk = make_ushort4(f2bf(acc[i][j][0] + bv), f2bf(acc[i][j][1] + bv),
                                  f2bf(acc[i][j][2] + bv), f2bf(acc[i][j][3] + bv));
        *(ushort4*)(Vout + ((size_t)(bb * 8 + hh) * 64 + dd) * L + keyl) = pk;
      } else {
#pragma unroll
        for (int r = 0; r < 4; ++r) {
          float v = acc[i][j][r] + bv;
          if (EPI == 1) v = fmaxf(v, 0.f);
          if (EPI == 3) v *= qscale;
          if (EPI == 2)
            outf[(size_t)(row + r) * N + col] = v;
          else
            ((unsigned short*)Cout)[(size_t)(row + r) * N + col] = f2bf(v);
        }
      }
    }
  }
}

// ---------------- banded flash attention (v11 = v9 + Q-prescale + occ 5) ------
// Round-3 v9 inner loop restored verbatim (the round-4 dead-half skip put
// branches inside the unrolled ds_read->MFMA chain and DOUBLED attn time:
// 42.6 us, MfmaUtil 3.9% -- rocprof r5). Only branch-free deltas kept:
// Q pre-scaled in QKV epilogue (exp without mul) and occupancy 4->5 blocks/CU
// (LDS 32 KB x 5 = 160 KB exact; VGPR 64 allows it; was 34.5% occupancy).
__global__ __launch_bounds__(256, 5)
void k_attn(const unsigned short* __restrict__ QKV, const unsigned short* __restrict__ Vg,
            unsigned short* __restrict__ attnb, const int* __restrict__ wptr) {
  const int W = wptr[0];  // 128
  __shared__ unsigned short Kt[2][4096];  // [key][slot], slot = dpart ^ sw2(key)
  __shared__ unsigned short Vt[2][4096];  // [d][slot],   slot = kpart ^ (d&7)
  const int tid = threadIdx.x;
  const int wave = tid >> 6, lane = tid & 63;
  const int quad = lane >> 4, l16 = lane & 15;
  const int bid = (int)((blockIdx.x & 7) * (gridDim.x >> 3) + (blockIdx.x >> 3));
  const int qt = bid & 63, h = (bid >> 6) & 7, b = bid >> 9;  // qt fastest
  const int q0blk = qt * 64;
  const int q0 = q0blk + wave * 16;

  const unsigned short* Kbase = QKV + (size_t)(b * L) * 1536 + 512 + h * 64;
  const unsigned short* Vh = Vg + (size_t)(b * 8 + h) * 64 * L;  // [d][key]

  auto stage = [&](int buf, int jbg) {
#pragma unroll
    for (int i = 0; i < 2; ++i) {
      int c = i * 256 + tid;
      int kr = c >> 3;
      int key = jbg + kr;
      int keyc = key < 0 ? 0 : (key > L - 1 ? L - 1 : key);  // P=0 there
      int dpart = (c & 7) ^ (kr & 7) ^ (((kr >> 3) & 3) << 1);  // inv of sw2
      gl_lds16(Kbase + (size_t)keyc * 1536 + dpart * 8,
               &Kt[buf][(i * 256 + wave * 64) * 8]);
    }
#pragma unroll
    for (int i = 0; i < 2; ++i) {
      int c = i * 256 + tid;
      int d = c >> 3;
      int kpart = (c & 7) ^ (d & 7);
      int kb = jbg + kpart * 8;
      kb = kb < 0 ? 0 : (kb > L - 8 ? L - 8 : kb);  // 8-aligned, P=0 where invalid
      gl_lds16(Vh + (size_t)d * L + kb,
               &Vt[buf][(i * 256 + wave * 64) * 8]);
    }
  };

  const unsigned short* Qp = QKV + (size_t)(b * L + q0 + l16) * 1536 + h * 64;
  short8 qf0 = *(const short8*)(Qp + quad * 8);
  short8 qf1 = *(const short8*)(Qp + 32 + quad * 8);

  // per-tile K fragment offsets (iteration-invariant): A-row a=quad*4+r maps
  // to key (tt>>1)*32 + 8*quad + (tt&1)*4 + r, i.e. lane l16 loads
  // krow = (tt>>1)*32 + 8*(l16>>2) + (tt&1)*4 + (l16&3).
  int koff[4][2];
#pragma unroll
  for (int tt = 0; tt < 4; ++tt) {
    int krow = (tt >> 1) * 32 + ((l16 >> 2) << 3) + (tt & 1) * 4 + (l16 & 3);
    int s2 = (krow & 7) ^ (((krow >> 3) & 3) << 1);
    koff[tt][0] = (krow * 8 + (quad ^ s2)) * 8;
    koff[tt][1] = (krow * 8 + ((quad + 4) ^ s2)) * 8;
  }
  int voff[4][2];
#pragma unroll
  for (int nt = 0; nt < 4; ++nt) {
    int d = nt * 16 + l16;
    voff[nt][0] = (d * 8 + (quad ^ (d & 7))) * 8;
    voff[nt][1] = (d * 8 + ((quad + 4) ^ (d & 7))) * 8;
  }

  const floatx4 fzero = {0.f, 0.f, 0.f, 0.f};
  floatx4 o[4];
#pragma unroll
  for (int i = 0; i < 4; ++i) o[i] = fzero;
  float lsum = 0.f;
  const int q = q0 + l16;

  stage(0, q0blk - 128);
  __syncthreads();

  for (int it = 0; it < 5; ++it) {  // 5 x 64-key tiles cover the 320-key band
    const int jbg = q0blk - 128 + it * 64;
    if (it < 4) stage((it + 1) & 1, jbg + 64);  // prefetch next tile (async DMA)
    const unsigned short* lk = Kt[it & 1];
    const unsigned short* lv = Vt[it & 1];
    // wave-uniform: whole 16q x 64key sub-tile inside band & bounds?
    const bool fast = (jbg >= 0) && (jbg + 64 <= L) &&
                      (q0 + 15 - jbg <= W) && (jbg + 63 - q0 <= W);
    unsigned pu[8];
#pragma unroll
    for (int tt = 0; tt < 4; ++tt) {
      const short8 kf0 = *(const short8*)&lk[koff[tt][0]];
      const short8 kf1 = *(const short8*)&lk[koff[tt][1]];
      floatx4 z = fzero;
      z = __builtin_amdgcn_mfma_f32_16x16x32_bf16(kf0, qf0, z, 0, 0, 0);
      z = __builtin_amdgcn_mfma_f32_16x16x32_bf16(kf1, qf1, z, 0, 0, 0);
      float pv[4];
      if (fast) {
#pragma unroll
        for (int r = 0; r < 4; ++r) {
          float p = __expf(z[r]);  // Q pre-scaled by 1/sqrt(HD)
          lsum += p;
          pv[r] = p;
        }
      } else {
        const int kb0 = jbg + (tt >> 1) * 32 + quad * 8 + (tt & 1) * 4;
#pragma unroll
        for (int r = 0; r < 4; ++r) {
          int key = kb0 + r;
          int dd = q - key; dd = dd < 0 ? -dd : dd;
          bool okk = (key >= 0) && (key < L) && (dd <= W);
          float p = okk ? __expf(z[r]) : 0.f;  // fixed m=0, masked to 0
          lsum += p;
          pv[r] = p;
        }
      }
      unsigned lo2, hi2;  // v_cvt_pk_bf16_f32: src0 -> low 16, src1 -> high 16 (RNE)
      asm("v_cvt_pk_bf16_f32 %0, %1, %2" : "=v"(lo2) : "v"(pv[0]), "v"(pv[1]));
      asm("v_cvt_pk_bf16_f32 %0, %1, %2" : "=v"(hi2) : "v"(pv[2]), "v"(pv[3]));
      pu[tt * 2 + 0] = lo2;
      pu[tt * 2 + 1] = hi2;
    }
    union { unsigned u[4]; short8 v; } pa0, pa1;
    pa0.u[0] = pu[0]; pa0.u[1] = pu[1]; pa0.u[2] = pu[2]; pa0.u[3] = pu[3];
    pa1.u[0] = pu[4]; pa1.u[1] = pu[5]; pa1.u[2] = pu[6]; pa1.u[3] = pu[7];
#pragma unroll
    for (int nt = 0; nt < 4; ++nt) {
      const short8 vf0 = *(const short8*)&lv[voff[nt][0]];
      const short8 vf1 = *(const short8*)&lv[voff[nt][1]];
      o[nt] = __builtin_amdgcn_mfma_f32_16x16x32_bf16(pa0.v, vf0, o[nt], 0, 0, 0);
      o[nt] = __builtin_amdgcn_mfma_f32_16x16x32_bf16(pa1.v, vf1, o[nt], 0, 0, 0);
    }
    __syncthreads();  // drains next-tile DMA + guards buffer reuse
  }
  // row-sum: lane holds disjoint key subsets for q=q0+l16 -> reduce over quads
  lsum += __shfl_xor(lsum, 16, 64);
  lsum += __shfl_xor(lsum, 32, 64);
#pragma unroll
  for (int r = 0; r < 4; ++r) {
    float inv = 1.f / __shfl(lsum, quad * 4 + r, 64);  // sum for q=q0+quad*4+r
    size_t base = (size_t)(b * L + q0 + quad * 4 + r) * 512 + h * 64;
#pragma unroll
    for (int nt = 0; nt < 4; ++nt)
      attnb[base + nt * 16 + l16] = f2bf(o[nt][r] * inv);
  }
}

// ---------------- fused residual + LayerNorm ----------------------------------
// y = t0 (+ t1 if non-null) + res; out = LN(y)*g+b. RESBF: res is bf16.
template <int RESBF>
__global__ __launch_bounds__(256, 2)
void k_res_ln(const float* __restrict__ t0, const float* __restrict__ t1,
              const void* __restrict__ res,
              const float* __restrict__ gamma, const float* __restrict__ beta,
              float* __restrict__ outf, unsigned short* __restrict__ outb) {
  const int wave = threadIdx.x >> 6, lane = threadIdx.x & 63;
  const int row = blockIdx.x * 4 + wave;
  const float4* tv = (const float4*)(t0 + (size_t)row * D);
  float4 a0 = tv[lane], a1 = tv[lane + 64];
  float4 b0, b1;
  if (RESBF) {
    const ushort4* rv = (const ushort4*)((const unsigned short*)res + (size_t)row * D);
    ushort4 u0 = rv[lane], u1 = rv[lane + 64];
    b0 = make_float4(bf2f(u0.x), bf2f(u0.y), bf2f(u0.z), bf2f(u0.w));
    b1 = make_float4(bf2f(u1.x), bf2f(u1.y), bf2f(u1.z), bf2f(u1.w));
  } else {
    const float4* rv = (const float4*)((const float*)res + (size_t)row * D);
    b0 = rv[lane]; b1 = rv[lane + 64];
  }
  float4 y0 = make_float4(a0.x + b0.x, a0.y + b0.y, a0.z + b0.z, a0.w + b0.w);
  float4 y1 = make_float4(a1.x + b1.x, a1.y + b1.y, a1.z + b1.z, a1.w + b1.w);
  if (t1) {
    const float4* uv = (const float4*)(t1 + (size_t)row * D);
    float4 c0 = uv[lane], c1 = uv[lane + 64];
    y0.x += c0.x; y0.y += c0.y; y0.z += c0.z; y0.w += c0.w;
    y1.x += c1.x; y1.y += c1.y; y1.z += c1.z; y1.w += c1.w;
  }
  float s = y0.x + y0.y + y0.z + y0.w + y1.x + y1.y + y1.z + y1.w;
  float q = y0.x * y0.x + y0.y * y0.y + y0.z * y0.z + y0.w * y0.w +
            y1.x * y1.x + y1.y * y1.y + y1.z * y1.z + y1.w * y1.w;
#pragma unroll
  for (int d = 1; d < 64; d <<= 1) {
    s += __shfl_xor(s, d, 64);
    q += __shfl_xor(q, d, 64);
  }
  const float mean = s * (1.f / D);
  const float var = q * (1.f / D) - mean * mean;
  const float rstd = rsqrtf(var + LN_EPS);
  float4 g0 = ((const float4*)gamma)[lane], g1 = ((const float4*)gamma)[lane + 64];
  float4 e0 = ((const float4*)beta)[lane], e1 = ((const float4*)beta)[lane + 64];
  float4 o0 = make_float4((y0.x - mean) * rstd * g0.x + e0.x, (y0.y - mean) * rstd * g0.y + e0.y,
                          (y0.z - mean) * rstd * g0.z + e0.z, (y0.w - mean) * rstd * g0.w + e0.w);
  float4 o1 = make_float4((y1.x - mean) * rstd * g1.x + e1.x, (y1.y - mean) * rstd * g1.y + e1.y,
                          (y1.z - mean) * rstd * g1.z + e1.z, (y1.w - mean) * rstd * g1.w + e1.w);
  if (outf) {
    ((float4*)(outf + (size_t)row * D))[lane] = o0;
    ((float4*)(outf + (size_t)row * D))[lane + 64] = o1;
  }
  if (outb) {
    ((ushort4*)(outb + (size_t)row * D))[lane] =
        make_ushort4(f2bf(o0.x), f2bf(o0.y), f2bf(o0.z), f2bf(o0.w));
    ((ushort4*)(outb + (size_t)row * D))[lane + 64] =
        make_ushort4(f2bf(o1.x), f2bf(o1.y), f2bf(o1.z), f2bf(o1.w));
  }
}

}  // namespace

extern "C" void kernel_launch(void* const* d_in, const int* in_sizes, int n_in,
                              void* d_out, int out_size, void* d_ws, size_t ws_size,
                              hipStream_t stream) {
  const float* x   = (const float*)d_in[0];
  const float* Wq  = (const float*)d_in[1];
  const float* bq  = (const float*)d_in[2];
  const float* Wk  = (const float*)d_in[3];
  const float* bk  = (const float*)d_in[4];
  const float* Wv  = (const float*)d_in[5];
  const float* bv  = (const float*)d_in[6];
  const float* Wo  = (const float*)d_in[7];
  const float* bo  = (const float*)d_in[8];
  const float* g1  = (const float*)d_in[9];
  const float* be1 = (const float*)d_in[10];
  const float* W1  = (const float*)d_in[11];
  const float* b1  = (const float*)d_in[12];
  const float* W2  = (const float*)d_in[13];
  const float* b2  = (const float*)d_in[14];
  const float* g2  = (const float*)d_in[15];
  const float* be2 = (const float*)d_in[16];
  const int* wptr  = (const int*)d_in[17];
  float* out = (float*)d_out;

  char* w = (char*)d_ws;
  size_t off = 0;
  auto take = [&](size_t bytes) -> void* {
    void* p = w + off;
    off += (bytes + 255) & ~(size_t)255;
    return p;
  };
  unsigned short* Xb    = (unsigned short*)take((size_t)M * D * 2);      // 8 MiB
  unsigned short* QKVb  = (unsigned short*)take((size_t)M * 1536 * 2);   // 24 MiB
  unsigned short* attnb = (unsigned short*)take((size_t)M * D * 2);      // 8 MiB
  unsigned short* Vg    = (unsigned short*)take((size_t)M * D * 2);      // 8 MiB (V^T per head)
  unsigned short* WqkvT = (unsigned short*)take((size_t)1536 * 512 * 2); // 1.5 MiB
  unsigned short* WoT   = (unsigned short*)take((size_t)512 * 512 * 2);  // 0.5 MiB
  unsigned short* W1T   = (unsigned short*)take((size_t)2048 * 512 * 2); // 2 MiB
  unsigned short* W2T   = (unsigned short*)take((size_t)512 * 2048 * 2); // 2 MiB
  float* bqkv           = (float*)take(1536 * 4);
  float* tbuf           = (float*)take((size_t)2 * M * D * 4);           // 32 MiB (2 split-K partials)
  unsigned short* hb    = (unsigned short*)take((size_t)M * D * 2);      // 8 MiB
  unsigned short* ffb   = (unsigned short*)take((size_t)M * FF * 2);     // 32 MiB

  k_prep<<<4870, 256, 0, stream>>>(x, Wq, Wk, Wv, Wo, W1, W2, bq, bk, bv,
                                   Xb, WqkvT, WoT, W1T, W2T, bqkv);
  // QKV: Q (pre-scaled) / K -> QKVb, V -> Vg transposed
  k_gemm<3><<<dim3(12, 64, 1), 256, 0, stream>>>(Xb, WqkvT, bqkv, QKVb, Vg, 512, 1536);
  k_attn<<<B * H * (L / 64), 256, 0, stream>>>(QKVb, Vg, attnb, wptr);
  k_gemm<2><<<dim3(4, 64, 2), 256, 0, stream>>>(attnb, WoT, bo, tbuf, nullptr, 256, 512);
  // h = LN1(x + t0 + t1) -> hb (bf16 only; fp32 h dropped)
  k_res_ln<0><<<M / 4, 256, 0, stream>>>(tbuf, tbuf + (size_t)M * D, x, g1, be1, nullptr, hb);
  k_gemm<1><<<dim3(16, 64, 1), 256, 0, stream>>>(hb, W1T, b1, ffb, nullptr, 512, 2048);
  k_gemm<2><<<dim3(4, 64, 2), 256, 0, stream>>>(ffb, W2T, b2, tbuf, nullptr, 1024, 512);
  // out = LN2(hb + t0 + t1), residual from bf16 h
  k_res_ln<1><<<M / 4, 256, 0, stream>>>(tbuf, tbuf + (size_t)M * D, hb, g2, be2, out, nullptr);
}

// Round 8
// 233.244 us; speedup vs baseline: 1.1091x; 1.0053x over previous
//
#include <hip/hip_runtime.h>

namespace {

constexpr int B = 2, L = 4096, D = 512, H = 8, FF = 2048;
constexpr int M = B * L; // 8192
constexpr float LN_EPS = 1e-5f;

typedef __attribute__((ext_vector_type(8))) short short8;
typedef __attribute__((ext_vector_type(4))) float floatx4;

typedef __attribute__((address_space(3))) unsigned int lds_uint;
typedef const __attribute__((address_space(1))) unsigned int glob_uint;

__device__ __forceinline__ void gl_lds16(const unsigned short* g, unsigned short* l) {
  // async global->LDS, 16B/lane; LDS dest = wave-uniform base + lane*16 (m104)
  __builtin_amdgcn_global_load_lds((glob_uint*)g, (lds_uint*)l, 16, 0, 0);
}

__device__ __forceinline__ unsigned short f2bf(float f) {
  union { float f; unsigned u; } v; v.f = f;
  unsigned r = v.u + 0x7FFFu + ((v.u >> 16) & 1u);
  return (unsigned short)(r >> 16);
}

__device__ __forceinline__ float bf2f(unsigned short b) {
  union { unsigned u; float f; } v; v.u = ((unsigned)b) << 16;
  return v.f;
}

// ---------------- fused prep: x->bf16 + bias concat + weight transposes ------
__global__ __launch_bounds__(256)
void k_prep(const float* __restrict__ x,
            const float* __restrict__ Wq, const float* __restrict__ Wk,
            const float* __restrict__ Wv, const float* __restrict__ Wo,
            const float* __restrict__ W1, const float* __restrict__ W2,
            const float* __restrict__ bq, const float* __restrict__ bk,
            const float* __restrict__ bv,
            unsigned short* __restrict__ Xb,
            unsigned short* __restrict__ WqkvT, unsigned short* __restrict__ WoT,
            unsigned short* __restrict__ W1T, unsigned short* __restrict__ W2T,
            float* __restrict__ bqkv) {
  __shared__ unsigned short tile[64 * 72];
  if (blockIdx.x < 4102) {
    int tid = blockIdx.x * blockDim.x + threadIdx.x;
    if (tid < 1048576) {  // x: 4 elems per thread (M*D = 4194304)
      float4 v = ((const float4*)x)[tid];
      ((ushort4*)Xb)[tid] = make_ushort4(f2bf(v.x), f2bf(v.y), f2bf(v.z), f2bf(v.w));
      return;
    }
    int u = tid - 1048576;
    if (u < 1536) bqkv[u] = (u < 512) ? bq[u] : (u < 1024 ? bk[u - 512] : bv[u - 1024]);
    return;
  }
  const int t = blockIdx.x - 4102;
  const float* src; unsigned short* dst; int Ns, Kd, n0, k0, nsrc0;
  if (t < 192) {        // WqkvT [1536][512] from Wq/Wk/Wv [512][512]
    int nt = t % 24, kt = t / 24; int ng = nt * 64;
    src = ng < 512 ? Wq : (ng < 1024 ? Wk : Wv);
    Ns = 512; Kd = 512; n0 = ng; nsrc0 = ng & 511; k0 = kt * 64; dst = WqkvT;
  } else if (t < 256) { // WoT [512][512] from Wo [512][512]
    int u = t - 192; int nt = u % 8, kt = u / 8;
    src = Wo; Ns = 512; Kd = 512; n0 = nt * 64; nsrc0 = n0; k0 = kt * 64; dst = WoT;
  } else if (t < 512) { // W1T [2048][512] from W1 [512][2048]
    int u = t - 256; int nt = u % 32, kt = u / 32;
    src = W1; Ns = 2048; Kd = 512; n0 = nt * 64; nsrc0 = n0; k0 = kt * 64; dst = W1T;
  } else {              // W2T [512][2048] from W2 [2048][512]
    int u = t - 512; int nt = u % 8, kt = u / 8;
    src = W2; Ns = 512; Kd = 2048; n0 = nt * 64; nsrc0 = n0; k0 = kt * 64; dst = W2T;
  }
  const int tid = threadIdx.x;
  {
    int r = tid >> 2, cs = (tid & 3) * 16;  // src row k0+r, 16 cols
    const float4* sp = (const float4*)(src + (size_t)(k0 + r) * Ns + nsrc0 + cs);
    unsigned short* tp = &tile[r * 72 + cs];
#pragma unroll
    for (int i = 0; i < 4; ++i) {
      float4 v = sp[i];
      tp[i * 4 + 0] = f2bf(v.x); tp[i * 4 + 1] = f2bf(v.y);
      tp[i * 4 + 2] = f2bf(v.z); tp[i * 4 + 3] = f2bf(v.w);
    }
  }
  __syncthreads();
  {
    int n = tid >> 2, ks = (tid & 3) * 16;  // dst row n0+n, 16 k's
    unsigned short buf[16];
#pragma unroll
    for (int e = 0; e < 16; ++e) buf[e] = tile[(ks + e) * 72 + n];
    unsigned short* dp = dst + (size_t)(n0 + n) * Kd + k0 + ks;
    *(short8*)dp = *(const short8*)&buf[0];
    *(short8*)(dp + 8) = *(const short8*)&buf[8];
  }
}

// ---------------- bf16 MFMA GEMM (double-buffered DMA staging) ---------------
// EPI: 0 = bf16 out, 1 = bf16 out + ReLU, 2 = f32 out (split-K partials),
//      3 = QKV fused: Q cols scaled by 1/sqrt(HD) (attn scale folded in),
//          Q/K cols -> Cout (bf16), V cols -> Vout TRANSPOSED ([b][h][d][key]).
// Block ids are XCD-chunk remapped (T1).
template <int EPI>
__global__ __launch_bounds__(256, 3)
void k_gemm(const unsigned short* __restrict__ A, const unsigned short* __restrict__ BT,
            const float* __restrict__ bias, void* __restrict__ Cout,
            unsigned short* __restrict__ Vout,
            const int klen, const int N) {
  __shared__ unsigned short lA[2][128 * 32];
  __shared__ unsigned short lB[2][128 * 32];
  // XCD-chunked bijective remap (all grids have total % 8 == 0)
  unsigned flat = blockIdx.x + gridDim.x * (blockIdx.y + gridDim.y * blockIdx.z);
  const unsigned chunk = (gridDim.x * gridDim.y * gridDim.z) >> 3;
  flat = (flat & 7) * chunk + (flat >> 3);
  const unsigned bx = flat % gridDim.x;
  const unsigned rest = flat / gridDim.x;
  const unsigned by = rest % gridDim.y;
  const unsigned bz = rest / gridDim.y;

  const int tid = threadIdx.x;
  const int wave = tid >> 6, lane = tid & 63;
  const int quad = lane >> 4, l16 = lane & 15;
  const int m0 = by * 128, n0 = bx * 128;
  const int wm = (wave >> 1) * 64, wn = (wave & 1) * 64;
  const int kbeg = bz * klen;
  const size_t Kdim = (size_t)klen * gridDim.z;

  const floatx4 fzero = {0.f, 0.f, 0.f, 0.f};
  floatx4 acc[4][4];
#pragma unroll
  for (int i = 0; i < 4; ++i)
#pragma unroll
    for (int j = 0; j < 4; ++j) acc[i][j] = fzero;

  const int r0 = tid >> 2, o0 = (tid & 3) * 8;
  const int r1 = (256 + tid) >> 2, o1 = (tid & 3) * 8;
  const unsigned short* Ag0 = A + (size_t)(m0 + r0) * Kdim + kbeg + o0;
  const unsigned short* Ag1 = A + (size_t)(m0 + r1) * Kdim + kbeg + o1;
  const unsigned short* Bg0 = BT + (size_t)(n0 + r0) * Kdim + kbeg + o0;
  const unsigned short* Bg1 = BT + (size_t)(n0 + r1) * Kdim + kbeg + o1;

  auto stage = [&](int buf, int kt) {
    gl_lds16(Ag0 + kt, &lA[buf][wave * 512]);
    gl_lds16(Ag1 + kt, &lA[buf][(4 + wave) * 512]);
    gl_lds16(Bg0 + kt, &lB[buf][wave * 512]);
    gl_lds16(Bg1 + kt, &lB[buf][(4 + wave) * 512]);
  };

  stage(0, 0);
  __syncthreads();  // drain first tile's DMA

  int buf = 0;
  for (int kt = 0; kt < klen; kt += 32, buf ^= 1) {
    if (kt + 32 < klen) stage(buf ^ 1, kt + 32);  // async prefetch of next tile
    short8 af[4], bf[4];
#pragma unroll
    for (int i = 0; i < 4; ++i)
      af[i] = *(const short8*)&lA[buf][(wm + i * 16 + l16) * 32 + quad * 8];
#pragma unroll
    for (int j = 0; j < 4; ++j)
      bf[j] = *(const short8*)&lB[buf][(wn + j * 16 + l16) * 32 + quad * 8];
#pragma unroll
    for (int i = 0; i < 4; ++i)
#pragma unroll
      for (int j = 0; j < 4; ++j)
        acc[i][j] = __builtin_amdgcn_mfma_f32_16x16x32_bf16(af[i], bf[j], acc[i][j], 0, 0, 0);
    __syncthreads();  // drains prefetch DMA + guards buffer reuse
  }

  float* outf = (float*)Cout + (size_t)bz * M * N;
  const bool vblock = (EPI == 3) && (n0 >= 1024);  // block-uniform
  const float qscale = (EPI == 3 && n0 < 512) ? 0.125f : 1.f;  // Q cols pre-scaled
#pragma unroll
  for (int j = 0; j < 4; ++j) {
    const int col = n0 + wn + j * 16 + l16;
    const float bv = (bz == 0) ? bias[col] : 0.f;
#pragma unroll
    for (int i = 0; i < 4; ++i) {
      const int row = m0 + wm + i * 16 + quad * 4;
      if (EPI == 3 && vblock) {
        const int hh = (col - 1024) >> 6, dd = (col - 1024) & 63;
        const int bb = row >> 12, keyl = row & 4095;  // 128-tiles never cross b
        ushort4 pk = make_ushort4(f2bf(acc[i][j][0] + bv), f2bf(acc[i][j][1] + bv),
                                  f2bf(acc[i][j][2] + bv), f2bf(acc[i][j][3] + bv));
        *(ushort4*)(Vout + ((size_t)(bb * 8 + hh) * 64 + dd) * L + keyl) = pk;
      } else {
#pragma unroll
        for (int r = 0; r < 4; ++r) {
          float v = acc[i][j][r] + bv;
          if (EPI == 1) v = fmaxf(v, 0.f);
          if (EPI == 3) v *= qscale;
          if (EPI == 2)
            outf[(size_t)(row + r) * N + col] = v;
          else
            ((unsigned short*)Cout)[(size_t)(row + r) * N + col] = f2bf(v);
        }
      }
    }
  }
}

// ---------------- bf16 MFMA GEMM, 64x128 tile (latency-optimized) -------------
// For shallow-grid shapes (FFN1: 1024 blocks at 128^2 = only 4 blocks/CU of
// work; rocprof r6: MfmaUtil 14%, Occupancy 36%, HBM 25% -> latency-bound).
// 64M x 128N, BK=32, 4 waves (2M x 2N), acc[2][4], LDS 24 KiB dbuf ->
// ~6 blocks/CU resource-fit, FFN1 grid 16x128 = 2048 blocks = 8/CU deep.
// Same ascending-BK accumulation order as k_gemm -> bit-identical output.
template <int EPI>
__global__ __launch_bounds__(256, 5)
void k_gemm64(const unsigned short* __restrict__ A, const unsigned short* __restrict__ BT,
              const float* __restrict__ bias, void* __restrict__ Cout,
              const int klen, const int N) {
  __shared__ unsigned short lA[2][64 * 32];
  __shared__ unsigned short lB[2][128 * 32];
  // XCD-chunked bijective remap (grid total % 8 == 0)
  unsigned flat = blockIdx.x + gridDim.x * blockIdx.y;
  const unsigned chunk = (gridDim.x * gridDim.y) >> 3;
  flat = (flat & 7) * chunk + (flat >> 3);
  const unsigned bx = flat % gridDim.x;
  const unsigned by = flat / gridDim.x;

  const int tid = threadIdx.x;
  const int wave = tid >> 6, lane = tid & 63;
  const int quad = lane >> 4, l16 = lane & 15;
  const int m0 = by * 64, n0 = bx * 128;
  const int wm = (wave >> 1) * 32, wn = (wave & 1) * 64;
  const size_t Kdim = (size_t)klen;

  const floatx4 fzero = {0.f, 0.f, 0.f, 0.f};
  floatx4 acc[2][4];
#pragma unroll
  for (int i = 0; i < 2; ++i)
#pragma unroll
    for (int j = 0; j < 4; ++j) acc[i][j] = fzero;

  const int r0 = tid >> 2, o0 = (tid & 3) * 8;  // 64 rows x 4 granules
  const unsigned short* Ag  = A + (size_t)(m0 + r0) * Kdim + o0;
  const unsigned short* Bg0 = BT + (size_t)(n0 + r0) * Kdim + o0;
  const unsigned short* Bg1 = BT + (size_t)(n0 + 64 + r0) * Kdim + o0;

  auto stage = [&](int buf, int kt) {
    gl_lds16(Ag + kt, &lA[buf][wave * 512]);
    gl_lds16(Bg0 + kt, &lB[buf][wave * 512]);
    gl_lds16(Bg1 + kt, &lB[buf][(4 + wave) * 512]);
  };

  stage(0, 0);
  __syncthreads();  // drain first tile's DMA

  int buf = 0;
  for (int kt = 0; kt < klen; kt += 32, buf ^= 1) {
    if (kt + 32 < klen) stage(buf ^ 1, kt + 32);  // async prefetch of next tile
    short8 af[2], bf[4];
#pragma unroll
    for (int i = 0; i < 2; ++i)
      af[i] = *(const short8*)&lA[buf][(wm + i * 16 + l16) * 32 + quad * 8];
#pragma unroll
    for (int j = 0; j < 4; ++j)
      bf[j] = *(const short8*)&lB[buf][(wn + j * 16 + l16) * 32 + quad * 8];
#pragma unroll
    for (int i = 0; i < 2; ++i)
#pragma unroll
      for (int j = 0; j < 4; ++j)
        acc[i][j] = __builtin_amdgcn_mfma_f32_16x16x32_bf16(af[i], bf[j], acc[i][j], 0, 0, 0);
    __syncthreads();  // drains prefetch DMA + guards buffer reuse
  }

  unsigned short* outb = (unsigned short*)Cout;
#pragma unroll
  for (int j = 0; j < 4; ++j) {
    const int col = n0 + wn + j * 16 + l16;
    const float bv = bias[col];
#pragma unroll
    for (int i = 0; i < 2; ++i) {
      const int row = m0 + wm + i * 16 + quad * 4;
#pragma unroll
      for (int r = 0; r < 4; ++r) {
        float v = acc[i][j][r] + bv;
        if (EPI == 1) v = fmaxf(v, 0.f);
        outb[(size_t)(row + r) * N + col] = f2bf(v);
      }
    }
  }
}

// ---------------- banded flash attention (v11 = v9 + Q-prescale + occ 5) ------
__global__ __launch_bounds__(256, 5)
void k_attn(const unsigned short* __restrict__ QKV, const unsigned short* __restrict__ Vg,
            unsigned short* __restrict__ attnb, const int* __restrict__ wptr) {
  const int W = wptr[0];  // 128
  __shared__ unsigned short Kt[2][4096];  // [key][slot], slot = dpart ^ sw2(key)
  __shared__ unsigned short Vt[2][4096];  // [d][slot],   slot = kpart ^ (d&7)
  const int tid = threadIdx.x;
  const int wave = tid >> 6, lane = tid & 63;
  const int quad = lane >> 4, l16 = lane & 15;
  const int bid = (int)((blockIdx.x & 7) * (gridDim.x >> 3) + (blockIdx.x >> 3));
  const int qt = bid & 63, h = (bid >> 6) & 7, b = bid >> 9;  // qt fastest
  const int q0blk = qt * 64;
  const int q0 = q0blk + wave * 16;

  const unsigned short* Kbase = QKV + (size_t)(b * L) * 1536 + 512 + h * 64;
  const unsigned short* Vh = Vg + (size_t)(b * 8 + h) * 64 * L;  // [d][key]

  auto stage = [&](int buf, int jbg) {
#pragma unroll
    for (int i = 0; i < 2; ++i) {
      int c = i * 256 + tid;
      int kr = c >> 3;
      int key = jbg + kr;
      int keyc = key < 0 ? 0 : (key > L - 1 ? L - 1 : key);  // P=0 there
      int dpart = (c & 7) ^ (kr & 7) ^ (((kr >> 3) & 3) << 1);  // inv of sw2
      gl_lds16(Kbase + (size_t)keyc * 1536 + dpart * 8,
               &Kt[buf][(i * 256 + wave * 64) * 8]);
    }
#pragma unroll
    for (int i = 0; i < 2; ++i) {
      int c = i * 256 + tid;
      int d = c >> 3;
      int kpart = (c & 7) ^ (d & 7);
      int kb = jbg + kpart * 8;
      kb = kb < 0 ? 0 : (kb > L - 8 ? L - 8 : kb);  // 8-aligned, P=0 where invalid
      gl_lds16(Vh + (size_t)d * L + kb,
               &Vt[buf][(i * 256 + wave * 64) * 8]);
    }
  };

  const unsigned short* Qp = QKV + (size_t)(b * L + q0 + l16) * 1536 + h * 64;
  short8 qf0 = *(const short8*)(Qp + quad * 8);
  short8 qf1 = *(const short8*)(Qp + 32 + quad * 8);

  // per-tile K fragment offsets (iteration-invariant): A-row a=quad*4+r maps
  // to key (tt>>1)*32 + 8*quad + (tt&1)*4 + r, i.e. lane l16 loads
  // krow = (tt>>1)*32 + 8*(l16>>2) + (tt&1)*4 + (l16&3).
  int koff[4][2];
#pragma unroll
  for (int tt = 0; tt < 4; ++tt) {
    int krow = (tt >> 1) * 32 + ((l16 >> 2) << 3) + (tt & 1) * 4 + (l16 & 3);
    int s2 = (krow & 7) ^ (((krow >> 3) & 3) << 1);
    koff[tt][0] = (krow * 8 + (quad ^ s2)) * 8;
    koff[tt][1] = (krow * 8 + ((quad + 4) ^ s2)) * 8;
  }
  int voff[4][2];
#pragma unroll
  for (int nt = 0; nt < 4; ++nt) {
    int d = nt * 16 + l16;
    voff[nt][0] = (d * 8 + (quad ^ (d & 7))) * 8;
    voff[nt][1] = (d * 8 + ((quad + 4) ^ (d & 7))) * 8;
  }

  const floatx4 fzero = {0.f, 0.f, 0.f, 0.f};
  floatx4 o[4];
#pragma unroll
  for (int i = 0; i < 4; ++i) o[i] = fzero;
  float lsum = 0.f;
  const int q = q0 + l16;

  stage(0, q0blk - 128);
  __syncthreads();

  for (int it = 0; it < 5; ++it) {  // 5 x 64-key tiles cover the 320-key band
    const int jbg = q0blk - 128 + it * 64;
    if (it < 4) stage((it + 1) & 1, jbg + 64);  // prefetch next tile (async DMA)
    const unsigned short* lk = Kt[it & 1];
    const unsigned short* lv = Vt[it & 1];
    // wave-uniform: whole 16q x 64key sub-tile inside band & bounds?
    const bool fast = (jbg >= 0) && (jbg + 64 <= L) &&
                      (q0 + 15 - jbg <= W) && (jbg + 63 - q0 <= W);
    unsigned pu[8];
#pragma unroll
    for (int tt = 0; tt < 4; ++tt) {
      const short8 kf0 = *(const short8*)&lk[koff[tt][0]];
      const short8 kf1 = *(const short8*)&lk[koff[tt][1]];
      floatx4 z = fzero;
      z = __builtin_amdgcn_mfma_f32_16x16x32_bf16(kf0, qf0, z, 0, 0, 0);
      z = __builtin_amdgcn_mfma_f32_16x16x32_bf16(kf1, qf1, z, 0, 0, 0);
      float pv[4];
      if (fast) {
#pragma unroll
        for (int r = 0; r < 4; ++r) {
          float p = __expf(z[r]);  // Q pre-scaled by 1/sqrt(HD)
          lsum += p;
          pv[r] = p;
        }
      } else {
        const int kb0 = jbg + (tt >> 1) * 32 + quad * 8 + (tt & 1) * 4;
#pragma unroll
        for (int r = 0; r < 4; ++r) {
          int key = kb0 + r;
          int dd = q - key; dd = dd < 0 ? -dd : dd;
          bool okk = (key >= 0) && (key < L) && (dd <= W);
          float p = okk ? __expf(z[r]) : 0.f;  // fixed m=0, masked to 0
          lsum += p;
          pv[r] = p;
        }
      }
      unsigned lo2, hi2;  // v_cvt_pk_bf16_f32: src0 -> low 16, src1 -> high 16 (RNE)
      asm("v_cvt_pk_bf16_f32 %0, %1, %2" : "=v"(lo2) : "v"(pv[0]), "v"(pv[1]));
      asm("v_cvt_pk_bf16_f32 %0, %1, %2" : "=v"(hi2) : "v"(pv[2]), "v"(pv[3]));
      pu[tt * 2 + 0] = lo2;
      pu[tt * 2 + 1] = hi2;
    }
    union { unsigned u[4]; short8 v; } pa0, pa1;
    pa0.u[0] = pu[0]; pa0.u[1] = pu[1]; pa0.u[2] = pu[2]; pa0.u[3] = pu[3];
    pa1.u[0] = pu[4]; pa1.u[1] = pu[5]; pa1.u[2] = pu[6]; pa1.u[3] = pu[7];
#pragma unroll
    for (int nt = 0; nt < 4; ++nt) {
      const short8 vf0 = *(const short8*)&lv[voff[nt][0]];
      const short8 vf1 = *(const short8*)&lv[voff[nt][1]];
      o[nt] = __builtin_amdgcn_mfma_f32_16x16x32_bf16(pa0.v, vf0, o[nt], 0, 0, 0);
      o[nt] = __builtin_amdgcn_mfma_f32_16x16x32_bf16(pa1.v, vf1, o[nt], 0, 0, 0);
    }
    __syncthreads();  // drains next-tile DMA + guards buffer reuse
  }
  // row-sum: lane holds disjoint key subsets for q=q0+l16 -> reduce over quads
  lsum += __shfl_xor(lsum, 16, 64);
  lsum += __shfl_xor(lsum, 32, 64);
#pragma unroll
  for (int r = 0; r < 4; ++r) {
    float inv = 1.f / __shfl(lsum, quad * 4 + r, 64);  // sum for q=q0+quad*4+r
    size_t base = (size_t)(b * L + q0 + quad * 4 + r) * 512 + h * 64;
#pragma unroll
    for (int nt = 0; nt < 4; ++nt)
      attnb[base + nt * 16 + l16] = f2bf(o[nt][r] * inv);
  }
}

// ---------------- fused residual + LayerNorm ----------------------------------
// y = t0 (+ t1 if non-null) + res; out = LN(y)*g+b. RESBF: res is bf16.
template <int RESBF>
__global__ __launch_bounds__(256, 2)
void k_res_ln(const float* __restrict__ t0, const float* __restrict__ t1,
              const void* __restrict__ res,
              const float* __restrict__ gamma, const float* __restrict__ beta,
              float* __restrict__ outf, unsigned short* __restrict__ outb) {
  const int wave = threadIdx.x >> 6, lane = threadIdx.x & 63;
  const int row = blockIdx.x * 4 + wave;
  const float4* tv = (const float4*)(t0 + (size_t)row * D);
  float4 a0 = tv[lane], a1 = tv[lane + 64];
  float4 b0, b1;
  if (RESBF) {
    const ushort4* rv = (const ushort4*)((const unsigned short*)res + (size_t)row * D);
    ushort4 u0 = rv[lane], u1 = rv[lane + 64];
    b0 = make_float4(bf2f(u0.x), bf2f(u0.y), bf2f(u0.z), bf2f(u0.w));
    b1 = make_float4(bf2f(u1.x), bf2f(u1.y), bf2f(u1.z), bf2f(u1.w));
  } else {
    const float4* rv = (const float4*)((const float*)res + (size_t)row * D);
    b0 = rv[lane]; b1 = rv[lane + 64];
  }
  float4 y0 = make_float4(a0.x + b0.x, a0.y + b0.y, a0.z + b0.z, a0.w + b0.w);
  float4 y1 = make_float4(a1.x + b1.x, a1.y + b1.y, a1.z + b1.z, a1.w + b1.w);
  if (t1) {
    const float4* uv = (const float4*)(t1 + (size_t)row * D);
    float4 c0 = uv[lane], c1 = uv[lane + 64];
    y0.x += c0.x; y0.y += c0.y; y0.z += c0.z; y0.w += c0.w;
    y1.x += c1.x; y1.y += c1.y; y1.z += c1.z; y1.w += c1.w;
  }
  float s = y0.x + y0.y + y0.z + y0.w + y1.x + y1.y + y1.z + y1.w;
  float q = y0.x * y0.x + y0.y * y0.y + y0.z * y0.z + y0.w * y0.w +
            y1.x * y1.x + y1.y * y1.y + y1.z * y1.z + y1.w * y1.w;
#pragma unroll
  for (int d = 1; d < 64; d <<= 1) {
    s += __shfl_xor(s, d, 64);
    q += __shfl_xor(q, d, 64);
  }
  const float mean = s * (1.f / D);
  const float var = q * (1.f / D) - mean * mean;
  const float rstd = rsqrtf(var + LN_EPS);
  float4 g0 = ((const float4*)gamma)[lane], g1 = ((const float4*)gamma)[lane + 64];
  float4 e0 = ((const float4*)beta)[lane], e1 = ((const float4*)beta)[lane + 64];
  float4 o0 = make_float4((y0.x - mean) * rstd * g0.x + e0.x, (y0.y - mean) * rstd * g0.y + e0.y,
                          (y0.z - mean) * rstd * g0.z + e0.z, (y0.w - mean) * rstd * g0.w + e0.w);
  float4 o1 = make_float4((y1.x - mean) * rstd * g1.x + e1.x, (y1.y - mean) * rstd * g1.y + e1.y,
                          (y1.z - mean) * rstd * g1.z + e1.z, (y1.w - mean) * rstd * g1.w + e1.w);
  if (outf) {
    ((float4*)(outf + (size_t)row * D))[lane] = o0;
    ((float4*)(outf + (size_t)row * D))[lane + 64] = o1;
  }
  if (outb) {
    ((ushort4*)(outb + (size_t)row * D))[lane] =
        make_ushort4(f2bf(o0.x), f2bf(o0.y), f2bf(o0.z), f2bf(o0.w));
    ((ushort4*)(outb + (size_t)row * D))[lane + 64] =
        make_ushort4(f2bf(o1.x), f2bf(o1.y), f2bf(o1.z), f2bf(o1.w));
  }
}

}  // namespace

extern "C" void kernel_launch(void* const* d_in, const int* in_sizes, int n_in,
                              void* d_out, int out_size, void* d_ws, size_t ws_size,
                              hipStream_t stream) {
  const float* x   = (const float*)d_in[0];
  const float* Wq  = (const float*)d_in[1];
  const float* bq  = (const float*)d_in[2];
  const float* Wk  = (const float*)d_in[3];
  const float* bk  = (const float*)d_in[4];
  const float* Wv  = (const float*)d_in[5];
  const float* bv  = (const float*)d_in[6];
  const float* Wo  = (const float*)d_in[7];
  const float* bo  = (const float*)d_in[8];
  const float* g1  = (const float*)d_in[9];
  const float* be1 = (const float*)d_in[10];
  const float* W1  = (const float*)d_in[11];
  const float* b1  = (const float*)d_in[12];
  const float* W2  = (const float*)d_in[13];
  const float* b2  = (const float*)d_in[14];
  const float* g2  = (const float*)d_in[15];
  const float* be2 = (const float*)d_in[16];
  const int* wptr  = (const int*)d_in[17];
  float* out = (float*)d_out;

  char* w = (char*)d_ws;
  size_t off = 0;
  auto take = [&](size_t bytes) -> void* {
    void* p = w + off;
    off += (bytes + 255) & ~(size_t)255;
    return p;
  };
  unsigned short* Xb    = (unsigned short*)take((size_t)M * D * 2);      // 8 MiB
  unsigned short* QKVb  = (unsigned short*)take((size_t)M * 1536 * 2);   // 24 MiB
  unsigned short* attnb = (unsigned short*)take((size_t)M * D * 2);      // 8 MiB
  unsigned short* Vg    = (unsigned short*)take((size_t)M * D * 2);      // 8 MiB (V^T per head)
  unsigned short* WqkvT = (unsigned short*)take((size_t)1536 * 512 * 2); // 1.5 MiB
  unsigned short* WoT   = (unsigned short*)take((size_t)512 * 512 * 2);  // 0.5 MiB
  unsigned short* W1T   = (unsigned short*)take((size_t)2048 * 512 * 2); // 2 MiB
  unsigned short* W2T   = (unsigned short*)take((size_t)512 * 2048 * 2); // 2 MiB
  float* bqkv           = (float*)take(1536 * 4);
  float* tbuf           = (float*)take((size_t)2 * M * D * 4);           // 32 MiB (2 split-K partials)
  unsigned short* hb    = (unsigned short*)take((size_t)M * D * 2);      // 8 MiB
  unsigned short* ffb   = (unsigned short*)take((size_t)M * FF * 2);     // 32 MiB

  k_prep<<<4870, 256, 0, stream>>>(x, Wq, Wk, Wv, Wo, W1, W2, bq, bk, bv,
                                   Xb, WqkvT, WoT, W1T, W2T, bqkv);
  // QKV: Q (pre-scaled) / K -> QKVb, V -> Vg transposed
  k_gemm<3><<<dim3(12, 64, 1), 256, 0, stream>>>(Xb, WqkvT, bqkv, QKVb, Vg, 512, 1536);
  k_attn<<<B * H * (L / 64), 256, 0, stream>>>(QKVb, Vg, attnb, wptr);
  k_gemm<2><<<dim3(4, 64, 2), 256, 0, stream>>>(attnb, WoT, bo, tbuf, nullptr, 256, 512);
  // h = LN1(x + t0 + t1) -> hb (bf16 only; fp32 h dropped)
  k_res_ln<0><<<M / 4, 256, 0, stream>>>(tbuf, tbuf + (size_t)M * D, x, g1, be1, nullptr, hb);
  // FFN1 on the 64x128-tile latency-optimized kernel: 2048 blocks = 8/CU deep
  k_gemm64<1><<<dim3(16, 128), 256, 0, stream>>>(hb, W1T, b1, ffb, 512, 2048);
  k_gemm<2><<<dim3(4, 64, 2), 256, 0, stream>>>(ffb, W2T, b2, tbuf, nullptr, 1024, 512);
  // out = LN2(hb + t0 + t1), residual from bf16 h
  k_res_ln<1><<<M / 4, 256, 0, stream>>>(tbuf, tbuf + (size_t)M * D, hb, g2, be2, out, nullptr);
}

// Round 9
// 226.780 us; speedup vs baseline: 1.1407x; 1.0285x over previous
//
#include <hip/hip_runtime.h>

namespace {

constexpr int B = 2, L = 4096, D = 512, H = 8, FF = 2048;
constexpr int M = B * L; // 8192
constexpr float LN_EPS = 1e-5f;

typedef __attribute__((ext_vector_type(8))) short short8;
typedef __attribute__((ext_vector_type(4))) float floatx4;

typedef __attribute__((address_space(3))) unsigned int lds_uint;
typedef const __attribute__((address_space(1))) unsigned int glob_uint;

__device__ __forceinline__ void gl_lds16(const unsigned short* g, unsigned short* l) {
  // async global->LDS, 16B/lane; LDS dest = wave-uniform base + lane*16 (m104)
  __builtin_amdgcn_global_load_lds((glob_uint*)g, (lds_uint*)l, 16, 0, 0);
}

__device__ __forceinline__ unsigned short f2bf(float f) {
  union { float f; unsigned u; } v; v.f = f;
  unsigned r = v.u + 0x7FFFu + ((v.u >> 16) & 1u);
  return (unsigned short)(r >> 16);
}

__device__ __forceinline__ float bf2f(unsigned short b) {
  union { unsigned u; float f; } v; v.u = ((unsigned)b) << 16;
  return v.f;
}

// ---------------- fused prep: x->bf16 + bias concat + weight transposes ------
__global__ __launch_bounds__(256)
void k_prep(const float* __restrict__ x,
            const float* __restrict__ Wq, const float* __restrict__ Wk,
            const float* __restrict__ Wv, const float* __restrict__ Wo,
            const float* __restrict__ W1, const float* __restrict__ W2,
            const float* __restrict__ bq, const float* __restrict__ bk,
            const float* __restrict__ bv,
            unsigned short* __restrict__ Xb,
            unsigned short* __restrict__ WqkvT, unsigned short* __restrict__ WoT,
            unsigned short* __restrict__ W1T, unsigned short* __restrict__ W2T,
            float* __restrict__ bqkv) {
  __shared__ unsigned short tile[64 * 72];
  if (blockIdx.x < 4102) {
    int tid = blockIdx.x * blockDim.x + threadIdx.x;
    if (tid < 1048576) {  // x: 4 elems per thread (M*D = 4194304)
      float4 v = ((const float4*)x)[tid];
      ((ushort4*)Xb)[tid] = make_ushort4(f2bf(v.x), f2bf(v.y), f2bf(v.z), f2bf(v.w));
      return;
    }
    int u = tid - 1048576;
    if (u < 1536) bqkv[u] = (u < 512) ? bq[u] : (u < 1024 ? bk[u - 512] : bv[u - 1024]);
    return;
  }
  const int t = blockIdx.x - 4102;
  const float* src; unsigned short* dst; int Ns, Kd, n0, k0, nsrc0;
  if (t < 192) {        // WqkvT [1536][512] from Wq/Wk/Wv [512][512]
    int nt = t % 24, kt = t / 24; int ng = nt * 64;
    src = ng < 512 ? Wq : (ng < 1024 ? Wk : Wv);
    Ns = 512; Kd = 512; n0 = ng; nsrc0 = ng & 511; k0 = kt * 64; dst = WqkvT;
  } else if (t < 256) { // WoT [512][512] from Wo [512][512]
    int u = t - 192; int nt = u % 8, kt = u / 8;
    src = Wo; Ns = 512; Kd = 512; n0 = nt * 64; nsrc0 = n0; k0 = kt * 64; dst = WoT;
  } else if (t < 512) { // W1T [2048][512] from W1 [512][2048]
    int u = t - 256; int nt = u % 32, kt = u / 32;
    src = W1; Ns = 2048; Kd = 512; n0 = nt * 64; nsrc0 = n0; k0 = kt * 64; dst = W1T;
  } else {              // W2T [512][2048] from W2 [2048][512]
    int u = t - 512; int nt = u % 8, kt = u / 8;
    src = W2; Ns = 512; Kd = 2048; n0 = nt * 64; nsrc0 = n0; k0 = kt * 64; dst = W2T;
  }
  const int tid = threadIdx.x;
  {
    int r = tid >> 2, cs = (tid & 3) * 16;  // src row k0+r, 16 cols
    const float4* sp = (const float4*)(src + (size_t)(k0 + r) * Ns + nsrc0 + cs);
    unsigned short* tp = &tile[r * 72 + cs];
#pragma unroll
    for (int i = 0; i < 4; ++i) {
      float4 v = sp[i];
      tp[i * 4 + 0] = f2bf(v.x); tp[i * 4 + 1] = f2bf(v.y);
      tp[i * 4 + 2] = f2bf(v.z); tp[i * 4 + 3] = f2bf(v.w);
    }
  }
  __syncthreads();
  {
    int n = tid >> 2, ks = (tid & 3) * 16;  // dst row n0+n, 16 k's
    unsigned short buf[16];
#pragma unroll
    for (int e = 0; e < 16; ++e) buf[e] = tile[(ks + e) * 72 + n];
    unsigned short* dp = dst + (size_t)(n0 + n) * Kd + k0 + ks;
    *(short8*)dp = *(const short8*)&buf[0];
    *(short8*)(dp + 8) = *(const short8*)&buf[8];
  }
}

// ---------------- bf16 MFMA GEMM (double-buffered DMA staging) ---------------
// EPI: 0 = bf16 out, 1 = bf16 out + ReLU, 2 = BF16 split-K partials (halves
//      tbuf round-trip traffic vs f32 -- round-8 change),
//      3 = QKV fused: Q cols scaled by 1/sqrt(HD) (attn scale folded in),
//          Q/K cols -> Cout (bf16), V cols -> Vout TRANSPOSED ([b][h][d][key]).
// Block ids are XCD-chunk remapped (T1).
template <int EPI>
__global__ __launch_bounds__(256, 3)
void k_gemm(const unsigned short* __restrict__ A, const unsigned short* __restrict__ BT,
            const float* __restrict__ bias, void* __restrict__ Cout,
            unsigned short* __restrict__ Vout,
            const int klen, const int N) {
  __shared__ unsigned short lA[2][128 * 32];
  __shared__ unsigned short lB[2][128 * 32];
  // XCD-chunked bijective remap (all grids have total % 8 == 0)
  unsigned flat = blockIdx.x + gridDim.x * (blockIdx.y + gridDim.y * blockIdx.z);
  const unsigned chunk = (gridDim.x * gridDim.y * gridDim.z) >> 3;
  flat = (flat & 7) * chunk + (flat >> 3);
  const unsigned bx = flat % gridDim.x;
  const unsigned rest = flat / gridDim.x;
  const unsigned by = rest % gridDim.y;
  const unsigned bz = rest / gridDim.y;

  const int tid = threadIdx.x;
  const int wave = tid >> 6, lane = tid & 63;
  const int quad = lane >> 4, l16 = lane & 15;
  const int m0 = by * 128, n0 = bx * 128;
  const int wm = (wave >> 1) * 64, wn = (wave & 1) * 64;
  const int kbeg = bz * klen;
  const size_t Kdim = (size_t)klen * gridDim.z;

  const floatx4 fzero = {0.f, 0.f, 0.f, 0.f};
  floatx4 acc[4][4];
#pragma unroll
  for (int i = 0; i < 4; ++i)
#pragma unroll
    for (int j = 0; j < 4; ++j) acc[i][j] = fzero;

  const int r0 = tid >> 2, o0 = (tid & 3) * 8;
  const int r1 = (256 + tid) >> 2, o1 = (tid & 3) * 8;
  const unsigned short* Ag0 = A + (size_t)(m0 + r0) * Kdim + kbeg + o0;
  const unsigned short* Ag1 = A + (size_t)(m0 + r1) * Kdim + kbeg + o1;
  const unsigned short* Bg0 = BT + (size_t)(n0 + r0) * Kdim + kbeg + o0;
  const unsigned short* Bg1 = BT + (size_t)(n0 + r1) * Kdim + kbeg + o1;

  auto stage = [&](int buf, int kt) {
    gl_lds16(Ag0 + kt, &lA[buf][wave * 512]);
    gl_lds16(Ag1 + kt, &lA[buf][(4 + wave) * 512]);
    gl_lds16(Bg0 + kt, &lB[buf][wave * 512]);
    gl_lds16(Bg1 + kt, &lB[buf][(4 + wave) * 512]);
  };

  stage(0, 0);
  __syncthreads();  // drain first tile's DMA

  int buf = 0;
  for (int kt = 0; kt < klen; kt += 32, buf ^= 1) {
    if (kt + 32 < klen) stage(buf ^ 1, kt + 32);  // async prefetch of next tile
    short8 af[4], bf[4];
#pragma unroll
    for (int i = 0; i < 4; ++i)
      af[i] = *(const short8*)&lA[buf][(wm + i * 16 + l16) * 32 + quad * 8];
#pragma unroll
    for (int j = 0; j < 4; ++j)
      bf[j] = *(const short8*)&lB[buf][(wn + j * 16 + l16) * 32 + quad * 8];
#pragma unroll
    for (int i = 0; i < 4; ++i)
#pragma unroll
      for (int j = 0; j < 4; ++j)
        acc[i][j] = __builtin_amdgcn_mfma_f32_16x16x32_bf16(af[i], bf[j], acc[i][j], 0, 0, 0);
    __syncthreads();  // drains prefetch DMA + guards buffer reuse
  }

  unsigned short* outp2 = (unsigned short*)Cout + (size_t)bz * M * N;  // EPI=2 partials
  const bool vblock = (EPI == 3) && (n0 >= 1024);  // block-uniform
  const float qscale = (EPI == 3 && n0 < 512) ? 0.125f : 1.f;  // Q cols pre-scaled
#pragma unroll
  for (int j = 0; j < 4; ++j) {
    const int col = n0 + wn + j * 16 + l16;
    const float bv = (bz == 0) ? bias[col] : 0.f;
#pragma unroll
    for (int i = 0; i < 4; ++i) {
      const int row = m0 + wm + i * 16 + quad * 4;
      if (EPI == 3 && vblock) {
        const int hh = (col - 1024) >> 6, dd = (col - 1024) & 63;
        const int bb = row >> 12, keyl = row & 4095;  // 128-tiles never cross b
        ushort4 pk = make_ushort4(f2bf(acc[i][j][0] + bv), f2bf(acc[i][j][1] + bv),
                                  f2bf(acc[i][j][2] + bv), f2bf(acc[i][j][3] + bv));
        *(ushort4*)(Vout + ((size_t)(bb * 8 + hh) * 64 + dd) * L + keyl) = pk;
      } else {
#pragma unroll
        for (int r = 0; r < 4; ++r) {
          float v = acc[i][j][r] + bv;
          if (EPI == 1) v = fmaxf(v, 0.f);
          if (EPI == 3) v *= qscale;
          if (EPI == 2)
            outp2[(size_t)(row + r) * N + col] = f2bf(v);
          else
            ((unsigned short*)Cout)[(size_t)(row + r) * N + col] = f2bf(v);
        }
      }
    }
  }
}

// ---------------- bf16 MFMA GEMM, 64x128 tile (latency-optimized) -------------
// Used for FFN1 (round-7: marginal win over 128^2, kept). Same ascending-BK
// accumulation order as k_gemm -> bit-identical output.
template <int EPI>
__global__ __launch_bounds__(256, 5)
void k_gemm64(const unsigned short* __restrict__ A, const unsigned short* __restrict__ BT,
              const float* __restrict__ bias, void* __restrict__ Cout,
              const int klen, const int N) {
  __shared__ unsigned short lA[2][64 * 32];
  __shared__ unsigned short lB[2][128 * 32];
  // XCD-chunked bijective remap (grid total % 8 == 0)
  unsigned flat = blockIdx.x + gridDim.x * blockIdx.y;
  const unsigned chunk = (gridDim.x * gridDim.y) >> 3;
  flat = (flat & 7) * chunk + (flat >> 3);
  const unsigned bx = flat % gridDim.x;
  const unsigned by = flat / gridDim.x;

  const int tid = threadIdx.x;
  const int wave = tid >> 6, lane = tid & 63;
  const int quad = lane >> 4, l16 = lane & 15;
  const int m0 = by * 64, n0 = bx * 128;
  const int wm = (wave >> 1) * 32, wn = (wave & 1) * 64;
  const size_t Kdim = (size_t)klen;

  const floatx4 fzero = {0.f, 0.f, 0.f, 0.f};
  floatx4 acc[2][4];
#pragma unroll
  for (int i = 0; i < 2; ++i)
#pragma unroll
    for (int j = 0; j < 4; ++j) acc[i][j] = fzero;

  const int r0 = tid >> 2, o0 = (tid & 3) * 8;  // 64 rows x 4 granules
  const unsigned short* Ag  = A + (size_t)(m0 + r0) * Kdim + o0;
  const unsigned short* Bg0 = BT + (size_t)(n0 + r0) * Kdim + o0;
  const unsigned short* Bg1 = BT + (size_t)(n0 + 64 + r0) * Kdim + o0;

  auto stage = [&](int buf, int kt) {
    gl_lds16(Ag + kt, &lA[buf][wave * 512]);
    gl_lds16(Bg0 + kt, &lB[buf][wave * 512]);
    gl_lds16(Bg1 + kt, &lB[buf][(4 + wave) * 512]);
  };

  stage(0, 0);
  __syncthreads();  // drain first tile's DMA

  int buf = 0;
  for (int kt = 0; kt < klen; kt += 32, buf ^= 1) {
    if (kt + 32 < klen) stage(buf ^ 1, kt + 32);  // async prefetch of next tile
    short8 af[2], bf[4];
#pragma unroll
    for (int i = 0; i < 2; ++i)
      af[i] = *(const short8*)&lA[buf][(wm + i * 16 + l16) * 32 + quad * 8];
#pragma unroll
    for (int j = 0; j < 4; ++j)
      bf[j] = *(const short8*)&lB[buf][(wn + j * 16 + l16) * 32 + quad * 8];
#pragma unroll
    for (int i = 0; i < 2; ++i)
#pragma unroll
      for (int j = 0; j < 4; ++j)
        acc[i][j] = __builtin_amdgcn_mfma_f32_16x16x32_bf16(af[i], bf[j], acc[i][j], 0, 0, 0);
    __syncthreads();  // drains prefetch DMA + guards buffer reuse
  }

  unsigned short* outb = (unsigned short*)Cout;
#pragma unroll
  for (int j = 0; j < 4; ++j) {
    const int col = n0 + wn + j * 16 + l16;
    const float bv = bias[col];
#pragma unroll
    for (int i = 0; i < 2; ++i) {
      const int row = m0 + wm + i * 16 + quad * 4;
#pragma unroll
      for (int r = 0; r < 4; ++r) {
        float v = acc[i][j][r] + bv;
        if (EPI == 1) v = fmaxf(v, 0.f);
        outb[(size_t)(row + r) * N + col] = f2bf(v);
      }
    }
  }
}

// ---------------- banded flash attention (v11 = v9 + Q-prescale + occ 5) ------
__global__ __launch_bounds__(256, 5)
void k_attn(const unsigned short* __restrict__ QKV, const unsigned short* __restrict__ Vg,
            unsigned short* __restrict__ attnb, const int* __restrict__ wptr) {
  const int W = wptr[0];  // 128
  __shared__ unsigned short Kt[2][4096];  // [key][slot], slot = dpart ^ sw2(key)
  __shared__ unsigned short Vt[2][4096];  // [d][slot],   slot = kpart ^ (d&7)
  const int tid = threadIdx.x;
  const int wave = tid >> 6, lane = tid & 63;
  const int quad = lane >> 4, l16 = lane & 15;
  const int bid = (int)((blockIdx.x & 7) * (gridDim.x >> 3) + (blockIdx.x >> 3));
  const int qt = bid & 63, h = (bid >> 6) & 7, b = bid >> 9;  // qt fastest
  const int q0blk = qt * 64;
  const int q0 = q0blk + wave * 16;

  const unsigned short* Kbase = QKV + (size_t)(b * L) * 1536 + 512 + h * 64;
  const unsigned short* Vh = Vg + (size_t)(b * 8 + h) * 64 * L;  // [d][key]

  auto stage = [&](int buf, int jbg) {
#pragma unroll
    for (int i = 0; i < 2; ++i) {
      int c = i * 256 + tid;
      int kr = c >> 3;
      int key = jbg + kr;
      int keyc = key < 0 ? 0 : (key > L - 1 ? L - 1 : key);  // P=0 there
      int dpart = (c & 7) ^ (kr & 7) ^ (((kr >> 3) & 3) << 1);  // inv of sw2
      gl_lds16(Kbase + (size_t)keyc * 1536 + dpart * 8,
               &Kt[buf][(i * 256 + wave * 64) * 8]);
    }
#pragma unroll
    for (int i = 0; i < 2; ++i) {
      int c = i * 256 + tid;
      int d = c >> 3;
      int kpart = (c & 7) ^ (d & 7);
      int kb = jbg + kpart * 8;
      kb = kb < 0 ? 0 : (kb > L - 8 ? L - 8 : kb);  // 8-aligned, P=0 where invalid
      gl_lds16(Vh + (size_t)d * L + kb,
               &Vt[buf][(i * 256 + wave * 64) * 8]);
    }
  };

  const unsigned short* Qp = QKV + (size_t)(b * L + q0 + l16) * 1536 + h * 64;
  short8 qf0 = *(const short8*)(Qp + quad * 8);
  short8 qf1 = *(const short8*)(Qp + 32 + quad * 8);

  // per-tile K fragment offsets (iteration-invariant): A-row a=quad*4+r maps
  // to key (tt>>1)*32 + 8*quad + (tt&1)*4 + r, i.e. lane l16 loads
  // krow = (tt>>1)*32 + 8*(l16>>2) + (tt&1)*4 + (l16&3).
  int koff[4][2];
#pragma unroll
  for (int tt = 0; tt < 4; ++tt) {
    int krow = (tt >> 1) * 32 + ((l16 >> 2) << 3) + (tt & 1) * 4 + (l16 & 3);
    int s2 = (krow & 7) ^ (((krow >> 3) & 3) << 1);
    koff[tt][0] = (krow * 8 + (quad ^ s2)) * 8;
    koff[tt][1] = (krow * 8 + ((quad + 4) ^ s2)) * 8;
  }
  int voff[4][2];
#pragma unroll
  for (int nt = 0; nt < 4; ++nt) {
    int d = nt * 16 + l16;
    voff[nt][0] = (d * 8 + (quad ^ (d & 7))) * 8;
    voff[nt][1] = (d * 8 + ((quad + 4) ^ (d & 7))) * 8;
  }

  const floatx4 fzero = {0.f, 0.f, 0.f, 0.f};
  floatx4 o[4];
#pragma unroll
  for (int i = 0; i < 4; ++i) o[i] = fzero;
  float lsum = 0.f;
  const int q = q0 + l16;

  stage(0, q0blk - 128);
  __syncthreads();

  for (int it = 0; it < 5; ++it) {  // 5 x 64-key tiles cover the 320-key band
    const int jbg = q0blk - 128 + it * 64;
    if (it < 4) stage((it + 1) & 1, jbg + 64);  // prefetch next tile (async DMA)
    const unsigned short* lk = Kt[it & 1];
    const unsigned short* lv = Vt[it & 1];
    // wave-uniform: whole 16q x 64key sub-tile inside band & bounds?
    const bool fast = (jbg >= 0) && (jbg + 64 <= L) &&
                      (q0 + 15 - jbg <= W) && (jbg + 63 - q0 <= W);
    unsigned pu[8];
#pragma unroll
    for (int tt = 0; tt < 4; ++tt) {
      const short8 kf0 = *(const short8*)&lk[koff[tt][0]];
      const short8 kf1 = *(const short8*)&lk[koff[tt][1]];
      floatx4 z = fzero;
      z = __builtin_amdgcn_mfma_f32_16x16x32_bf16(kf0, qf0, z, 0, 0, 0);
      z = __builtin_amdgcn_mfma_f32_16x16x32_bf16(kf1, qf1, z, 0, 0, 0);
      float pv[4];
      if (fast) {
#pragma unroll
        for (int r = 0; r < 4; ++r) {
          float p = __expf(z[r]);  // Q pre-scaled by 1/sqrt(HD)
          lsum += p;
          pv[r] = p;
        }
      } else {
        const int kb0 = jbg + (tt >> 1) * 32 + quad * 8 + (tt & 1) * 4;
#pragma unroll
        for (int r = 0; r < 4; ++r) {
          int key = kb0 + r;
          int dd = q - key; dd = dd < 0 ? -dd : dd;
          bool okk = (key >= 0) && (key < L) && (dd <= W);
          float p = okk ? __expf(z[r]) : 0.f;  // fixed m=0, masked to 0
          lsum += p;
          pv[r] = p;
        }
      }
      unsigned lo2, hi2;  // v_cvt_pk_bf16_f32: src0 -> low 16, src1 -> high 16 (RNE)
      asm("v_cvt_pk_bf16_f32 %0, %1, %2" : "=v"(lo2) : "v"(pv[0]), "v"(pv[1]));
      asm("v_cvt_pk_bf16_f32 %0, %1, %2" : "=v"(hi2) : "v"(pv[2]), "v"(pv[3]));
      pu[tt * 2 + 0] = lo2;
      pu[tt * 2 + 1] = hi2;
    }
    union { unsigned u[4]; short8 v; } pa0, pa1;
    pa0.u[0] = pu[0]; pa0.u[1] = pu[1]; pa0.u[2] = pu[2]; pa0.u[3] = pu[3];
    pa1.u[0] = pu[4]; pa1.u[1] = pu[5]; pa1.u[2] = pu[6]; pa1.u[3] = pu[7];
#pragma unroll
    for (int nt = 0; nt < 4; ++nt) {
      const short8 vf0 = *(const short8*)&lv[voff[nt][0]];
      const short8 vf1 = *(const short8*)&lv[voff[nt][1]];
      o[nt] = __builtin_amdgcn_mfma_f32_16x16x32_bf16(pa0.v, vf0, o[nt], 0, 0, 0);
      o[nt] = __builtin_amdgcn_mfma_f32_16x16x32_bf16(pa1.v, vf1, o[nt], 0, 0, 0);
    }
    __syncthreads();  // drains next-tile DMA + guards buffer reuse
  }
  // row-sum: lane holds disjoint key subsets for q=q0+l16 -> reduce over quads
  lsum += __shfl_xor(lsum, 16, 64);
  lsum += __shfl_xor(lsum, 32, 64);
#pragma unroll
  for (int r = 0; r < 4; ++r) {
    float inv = 1.f / __shfl(lsum, quad * 4 + r, 64);  // sum for q=q0+quad*4+r
    size_t base = (size_t)(b * L + q0 + quad * 4 + r) * 512 + h * 64;
#pragma unroll
    for (int nt = 0; nt < 4; ++nt)
      attnb[base + nt * 16 + l16] = f2bf(o[nt][r] * inv);
  }
}

// ---------------- fused residual + LayerNorm ----------------------------------
// y = t0 + t1 + res with t0/t1 BF16 split-K partials (round-8: halves tbuf
// traffic); res f32 (RESBF=0) or bf16 (RESBF=1). Contiguous 8 elems/lane
// (16B reads, fully coalesced). out = LN(y)*g+b -> outf (f32) / outb (bf16).
template <int RESBF>
__global__ __launch_bounds__(256, 2)
void k_res_ln(const unsigned short* __restrict__ t0, const unsigned short* __restrict__ t1,
              const void* __restrict__ res,
              const float* __restrict__ gamma, const float* __restrict__ beta,
              float* __restrict__ outf, unsigned short* __restrict__ outb) {
  const int wave = threadIdx.x >> 6, lane = threadIdx.x & 63;
  const int row = blockIdx.x * 4 + wave;
  const int e0 = lane * 8;  // 8 contiguous elems per lane
  union U8 { short8 v; unsigned short u[8]; };
  U8 a, c, rbuf;
  a.v = *(const short8*)(t0 + (size_t)row * D + e0);
  c.v = *(const short8*)(t1 + (size_t)row * D + e0);
  float y[8];
#pragma unroll
  for (int e = 0; e < 8; ++e) y[e] = bf2f(a.u[e]) + bf2f(c.u[e]);
  if (RESBF) {
    rbuf.v = *(const short8*)((const unsigned short*)res + (size_t)row * D + e0);
#pragma unroll
    for (int e = 0; e < 8; ++e) y[e] += bf2f(rbuf.u[e]);
  } else {
    const float4* rp = (const float4*)((const float*)res + (size_t)row * D + e0);
    float4 r0 = rp[0], r1 = rp[1];
    y[0] += r0.x; y[1] += r0.y; y[2] += r0.z; y[3] += r0.w;
    y[4] += r1.x; y[5] += r1.y; y[6] += r1.z; y[7] += r1.w;
  }
  float s = 0.f, q = 0.f;
#pragma unroll
  for (int e = 0; e < 8; ++e) { s += y[e]; q += y[e] * y[e]; }
#pragma unroll
  for (int d = 1; d < 64; d <<= 1) {
    s += __shfl_xor(s, d, 64);
    q += __shfl_xor(q, d, 64);
  }
  const float mean = s * (1.f / D);
  const float var = q * (1.f / D) - mean * mean;
  const float rstd = rsqrtf(var + LN_EPS);
  const float4* gp = (const float4*)(gamma + e0);
  const float4* bp = (const float4*)(beta + e0);
  float4 g0 = gp[0], g1 = gp[1], e0v = bp[0], e1v = bp[1];
  float o[8];
  o[0] = (y[0] - mean) * rstd * g0.x + e0v.x; o[1] = (y[1] - mean) * rstd * g0.y + e0v.y;
  o[2] = (y[2] - mean) * rstd * g0.z + e0v.z; o[3] = (y[3] - mean) * rstd * g0.w + e0v.w;
  o[4] = (y[4] - mean) * rstd * g1.x + e1v.x; o[5] = (y[5] - mean) * rstd * g1.y + e1v.y;
  o[6] = (y[6] - mean) * rstd * g1.z + e1v.z; o[7] = (y[7] - mean) * rstd * g1.w + e1v.w;
  if (outf) {
    float4* op = (float4*)(outf + (size_t)row * D + e0);
    op[0] = make_float4(o[0], o[1], o[2], o[3]);
    op[1] = make_float4(o[4], o[5], o[6], o[7]);
  }
  if (outb) {
    U8 w;
#pragma unroll
    for (int e = 0; e < 8; ++e) w.u[e] = f2bf(o[e]);
    *(short8*)(outb + (size_t)row * D + e0) = w.v;
  }
}

}  // namespace

extern "C" void kernel_launch(void* const* d_in, const int* in_sizes, int n_in,
                              void* d_out, int out_size, void* d_ws, size_t ws_size,
                              hipStream_t stream) {
  const float* x   = (const float*)d_in[0];
  const float* Wq  = (const float*)d_in[1];
  const float* bq  = (const float*)d_in[2];
  const float* Wk  = (const float*)d_in[3];
  const float* bk  = (const float*)d_in[4];
  const float* Wv  = (const float*)d_in[5];
  const float* bv  = (const float*)d_in[6];
  const float* Wo  = (const float*)d_in[7];
  const float* bo  = (const float*)d_in[8];
  const float* g1  = (const float*)d_in[9];
  const float* be1 = (const float*)d_in[10];
  const float* W1  = (const float*)d_in[11];
  const float* b1  = (const float*)d_in[12];
  const float* W2  = (const float*)d_in[13];
  const float* b2  = (const float*)d_in[14];
  const float* g2  = (const float*)d_in[15];
  const float* be2 = (const float*)d_in[16];
  const int* wptr  = (const int*)d_in[17];
  float* out = (float*)d_out;

  char* w = (char*)d_ws;
  size_t off = 0;
  auto take = [&](size_t bytes) -> void* {
    void* p = w + off;
    off += (bytes + 255) & ~(size_t)255;
    return p;
  };
  unsigned short* Xb    = (unsigned short*)take((size_t)M * D * 2);      // 8 MiB
  unsigned short* QKVb  = (unsigned short*)take((size_t)M * 1536 * 2);   // 24 MiB
  unsigned short* attnb = (unsigned short*)take((size_t)M * D * 2);      // 8 MiB
  unsigned short* Vg    = (unsigned short*)take((size_t)M * D * 2);      // 8 MiB (V^T per head)
  unsigned short* WqkvT = (unsigned short*)take((size_t)1536 * 512 * 2); // 1.5 MiB
  unsigned short* WoT   = (unsigned short*)take((size_t)512 * 512 * 2);  // 0.5 MiB
  unsigned short* W1T   = (unsigned short*)take((size_t)2048 * 512 * 2); // 2 MiB
  unsigned short* W2T   = (unsigned short*)take((size_t)512 * 2048 * 2); // 2 MiB
  float* bqkv           = (float*)take(1536 * 4);
  unsigned short* tbuf  = (unsigned short*)take((size_t)2 * M * D * 2);  // 16 MiB (2 bf16 split-K partials)
  unsigned short* hb    = (unsigned short*)take((size_t)M * D * 2);      // 8 MiB
  unsigned short* ffb   = (unsigned short*)take((size_t)M * FF * 2);     // 32 MiB

  k_prep<<<4870, 256, 0, stream>>>(x, Wq, Wk, Wv, Wo, W1, W2, bq, bk, bv,
                                   Xb, WqkvT, WoT, W1T, W2T, bqkv);
  // QKV: Q (pre-scaled) / K -> QKVb, V -> Vg transposed
  k_gemm<3><<<dim3(12, 64, 1), 256, 0, stream>>>(Xb, WqkvT, bqkv, QKVb, Vg, 512, 1536);
  k_attn<<<B * H * (L / 64), 256, 0, stream>>>(QKVb, Vg, attnb, wptr);
  k_gemm<2><<<dim3(4, 64, 2), 256, 0, stream>>>(attnb, WoT, bo, tbuf, nullptr, 256, 512);
  // h = LN1(x + t0 + t1) -> hb (bf16 only; fp32 h dropped)
  k_res_ln<0><<<M / 4, 256, 0, stream>>>(tbuf, tbuf + (size_t)M * D, x, g1, be1, nullptr, hb);
  // FFN1 on the 64x128-tile latency-optimized kernel: 2048 blocks = 8/CU deep
  k_gemm64<1><<<dim3(16, 128), 256, 0, stream>>>(hb, W1T, b1, ffb, 512, 2048);
  k_gemm<2><<<dim3(4, 64, 2), 256, 0, stream>>>(ffb, W2T, b2, tbuf, nullptr, 1024, 512);
  // out = LN2(hb + t0 + t1), residual from bf16 h
  k_res_ln<1><<<M / 4, 256, 0, stream>>>(tbuf, tbuf + (size_t)M * D, hb, g2, be2, out, nullptr);
}